// Round 1
// baseline (1284.383 us; speedup 1.0000x reference)
//
#include <hip/hip_runtime.h>

#define N_NODES 100000
#define N_EDGES 1600000
#define F_IN 512
#define F_HID 128
#define F_OUT 64

typedef unsigned int u32;
typedef __attribute__((ext_vector_type(8))) short bf16x8;
typedef __attribute__((ext_vector_type(4))) float f32x4;

__device__ float g7_bf2f(unsigned short u) {
    return __uint_as_float(((unsigned int)u) << 16);
}

__device__ unsigned short g7_f2bf(float f) {
    unsigned int u = __float_as_uint(f);
    u = u + 0x7fffu + ((u >> 16) & 1u);
    return (unsigned short)(u >> 16);
}

__device__ static inline void g7_gl2lds16(const void* g, void* l) {
    __builtin_amdgcn_global_load_lds(
        (const __attribute__((address_space(1))) u32*)g,
        (__attribute__((address_space(3))) u32*)l, 16, 0, 0);
}

__global__ void GCN_16716012716713_kernel() {}

__global__ void g7_zero(int* p, int n) {
    int i = blockIdx.x * blockDim.x + threadIdx.x;
    if (i < n) p[i] = 0;
}

// edge_index dtype probe: 1=int32, 0=int64 (int64 has all-zero high words)
__global__ void g7_iprobe(const int* raw, int* iflag) {
    if (blockIdx.x == 0 && threadIdx.x == 0) {
        int f = 0;
        for (int i = 0; i < 1024; i = i + 1) {
            if (raw[2 * i + 1] != 0) f = 1;
        }
        iflag[0] = f;
    }
}

// float dtype probe on x: 1=bf16, 0=fp32
__global__ void g7_fprobe(const unsigned int* xw, int* fflag) {
    if (blockIdx.x == 0 && threadIdx.x == 0) {
        int cnt = 0;
        for (int i = 0; i < 4096; i = i + 1) {
            unsigned int lo = xw[i] & 0xffffu;
            unsigned int e = (lo >> 7) & 0xffu;
            if (e >= 110u && e <= 140u) cnt = cnt + 1;
        }
        fflag[0] = (cnt > 2048) ? 1 : 0;
    }
}

__global__ void g7_pack(const int* raw, const int* iflag, int* ei) {
    int i = blockIdx.x * blockDim.x + threadIdx.x;
    if (i < 2 * N_EDGES) {
        if (iflag[0] == 0) {
            ei[i] = raw[2 * i];
        } else {
            ei[i] = raw[i];
        }
    }
}

__global__ void g7_cvt(const void* src, const int* fflag, float* dst, int n) {
    int i = blockIdx.x * blockDim.x + threadIdx.x;
    if (i < n) {
        if (fflag[0] == 1) {
            dst[i] = g7_bf2f(((const unsigned short*)src)[i]);
        } else {
            dst[i] = ((const float*)src)[i];
        }
    }
}

// W1T[n][k] bf16 (transposed W1) for the MFMA B-operand staging.
__global__ void g7_w1t(const void* W1, const int* fflag, unsigned short* W1T) {
    int i = blockIdx.x * blockDim.x + threadIdx.x;
    if (i < F_IN * F_HID) {
        int k = i >> 7;
        int n = i & 127;
        unsigned short v;
        if (fflag[0] == 1) {
            v = ((const unsigned short*)W1)[i];
        } else {
            v = g7_f2bf(((const float*)W1)[i]);
        }
        W1T[n * F_IN + k] = v;
    }
}

__global__ void g7_deg(const int* ei, int* deg) {
    int e = blockIdx.x * blockDim.x + threadIdx.x;
    if (e < N_EDGES) {
        atomicAdd(&deg[ei[N_EDGES + e]], 1);
    }
}

__global__ void g7_dinv(const int* deg, float* dinv) {
    int i = blockIdx.x * blockDim.x + threadIdx.x;
    if (i < N_NODES) {
        dinv[i] = rsqrtf((float)deg[i] + 1.0f);
    }
}

// ---- CSR build: block-sums -> serial scan of 391 block sums -> per-block scan ----
__global__ void g7_bsum(const int* deg, int* bsum) {
    __shared__ int s[256];
    int i = blockIdx.x * 256 + threadIdx.x;
    s[threadIdx.x] = (i < N_NODES) ? deg[i] : 0;
    __syncthreads();
    for (int off = 128; off > 0; off >>= 1) {
        if (threadIdx.x < off) s[threadIdx.x] += s[threadIdx.x + off];
        __syncthreads();
    }
    if (threadIdx.x == 0) bsum[blockIdx.x] = s[0];
}

__global__ void g7_bscan(const int* bsum, int* boff, int nblk, int* rowptr) {
    if (blockIdx.x == 0 && threadIdx.x == 0) {
        int acc = 0;
        for (int b = 0; b < nblk; b = b + 1) {
            boff[b] = acc;
            acc = acc + bsum[b];
        }
        rowptr[N_NODES] = acc;   // == N_EDGES
    }
}

__global__ void g7_scan(const int* deg, const int* boff, int* rowptr, int* cursor) {
    __shared__ int s[256];
    int i = blockIdx.x * 256 + threadIdx.x;
    int v = (i < N_NODES) ? deg[i] : 0;
    s[threadIdx.x] = v;
    __syncthreads();
    for (int off = 1; off < 256; off <<= 1) {
        int t = (threadIdx.x >= off) ? s[threadIdx.x - off] : 0;
        __syncthreads();
        s[threadIdx.x] += t;
        __syncthreads();
    }
    if (i < N_NODES) {
        int excl = s[threadIdx.x] - v + boff[blockIdx.x];
        rowptr[i] = excl;
        cursor[i] = excl;
    }
}

// scatter src ids into dst-grouped CSR order
__global__ void g7_scatter(const int* ei, int* cursor, int* csr) {
    int e = blockIdx.x * blockDim.x + threadIdx.x;
    if (e < N_EDGES) {
        int s = ei[e];
        int d = ei[N_EDGES + e];
        int pos = atomicAdd(&cursor[d], 1);
        csr[pos] = s;
    }
}

// ---- GEMM1 MFMA path (bf16 inputs): h1[100000,128] = x @ W1.
// BM=128, BN=128, BK=64, 256 thr = 4 waves (2x2), each wave 64x64 out.
// Double-buffered LDS (2 x (16KB A + 16KB B)), global_load_lds width-16,
// T2 XOR-swizzle via pre-swizzled global source (linear LDS dest). ----
__global__ __launch_bounds__(256) void g7_gemm1m(const void* x, const int* fflag,
                                                 const unsigned short* W1T, float* h1) {
    if (fflag[0] != 1) return;   // fp32 fallback handled by g7_gemm1
    __shared__ char sm[65536];
    const unsigned short* xb = (const unsigned short*)x;
    int tid = threadIdx.x;
    int m0 = blockIdx.x * 128;
    int w = tid >> 6;
    int lane = tid & 63;
    int r8 = lane >> 3;          // row within an 8-row staging instr
    int sub = lane & 7;          // 16B slot within a 128B row
    int wr = w >> 1, wc = w & 1; // wave grid 2x2
    int la = lane & 15;          // mfma row/col within 16
    int lk = lane >> 4;          // mfma k-group
    int swz = (la & 7) << 4;     // read-side XOR swizzle (bytes)

    f32x4 acc[4][4];
#pragma unroll
    for (int i = 0; i < 4; ++i)
#pragma unroll
        for (int j = 0; j < 4; ++j) acc[i][j] = (f32x4){0.f, 0.f, 0.f, 0.f};

    // stage one 128x64 A-tile + 64x128 B-tile (as 128 rows of W1T) into buf
    auto stage = [&](int buf, int k0) {
        char* As = sm + buf * 32768;
        char* Bs = As + 16384;
#pragma unroll
        for (int g = 0; g < 4; ++g) {
            int r = w * 32 + g * 8 + r8;              // LDS row 0..127 (lane-varying)
            int cb = (sub * 16) ^ ((r & 7) << 4);     // pre-swizzled source byte col
            int m = m0 + r;
            if (m >= N_NODES) m = N_NODES - 1;        // clamp: OOB rows discarded at store
            const char* srcA = (const char*)(xb + (long long)m * F_IN + k0) + cb;
            g7_gl2lds16(srcA, As + (w * 32 + g * 8) * 128);   // dest base wave-uniform
            const char* srcB = (const char*)(W1T + (long long)r * F_IN + k0) + cb;
            g7_gl2lds16(srcB, Bs + (w * 32 + g * 8) * 128);
        }
    };

    auto compute = [&](int buf) {
        char* As = sm + buf * 32768;
        char* Bs = As + 16384;
#pragma unroll
        for (int t = 0; t < 2; ++t) {
            int cb = (t * 64 + lk * 16) ^ swz;
            bf16x8 a[4], b[4];
#pragma unroll
            for (int i = 0; i < 4; ++i) {
                int rA = wr * 64 + i * 16 + la;
                a[i] = *(const bf16x8*)(As + rA * 128 + cb);
                int rB = wc * 64 + i * 16 + la;
                b[i] = *(const bf16x8*)(Bs + rB * 128 + cb);
            }
#pragma unroll
            for (int i = 0; i < 4; ++i)
#pragma unroll
                for (int j = 0; j < 4; ++j)
                    acc[i][j] = __builtin_amdgcn_mfma_f32_16x16x32_bf16(
                        a[i], b[j], acc[i][j], 0, 0, 0);
        }
    };

    stage(0, 0);
    __syncthreads();             // drains vmcnt: buf0 ready
    int cur = 0;
    for (int kt = 0; kt < 8; ++kt) {
        if (kt < 7) stage(cur ^ 1, (kt + 1) * 64);  // overlap next-tile loads w/ compute
        compute(cur);
        __syncthreads();         // drains staging loads + all ds_reads of cur
        cur ^= 1;
    }

    // epilogue: D[i=4*(lane>>4)+q][j=lane&15] per 16x16 fragment
#pragma unroll
    for (int i = 0; i < 4; ++i) {
#pragma unroll
        for (int j = 0; j < 4; ++j) {
            int n = wc * 64 + j * 16 + la;
#pragma unroll
            for (int q = 0; q < 4; ++q) {
                int m = m0 + wr * 64 + i * 16 + lk * 4 + q;
                if (m < N_NODES) {
                    h1[(long long)m * F_HID + n] = acc[i][j][q];
                }
            }
        }
    }
}

// ---- GEMM1 fp32 fallback: h1 = x @ W1f. BM=64, BN=128, BK=16, 256 thr, 8x4 micro ----
__global__ void g7_gemm1(const void* x, const int* fflag, const float* W,
                         float* h1) {
    if (fflag[0] == 1) return;   // bf16 path handled by g7_gemm1m
    __shared__ float Xs[16][68];
    __shared__ float Ws[16][128];
    int tid = threadIdx.x;
    int m0 = blockIdx.x * 64;
    int tx = tid & 31;
    int ty = tid >> 5;
    float acc[8][4];
#pragma unroll
    for (int i = 0; i < 8; ++i) {
#pragma unroll
        for (int j = 0; j < 4; ++j) acc[i][j] = 0.0f;
    }

    for (int k0 = 0; k0 < F_IN; k0 += 16) {
        int kk = tid & 15;
        int mm = tid >> 4;
#pragma unroll
        for (int r = 0; r < 4; ++r) {
            int m = m0 + mm + r * 16;
            float v = 0.0f;
            if (m < N_NODES) {
                long long gi = (long long)m * F_IN + k0 + kk;
                v = ((const float*)x)[gi];
            }
            Xs[kk][mm + r * 16] = v;
        }
#pragma unroll
        for (int r = 0; r < 8; ++r) {
            int i = r * 256 + tid;
            int wk = i >> 7;
            int wn = i & 127;
            Ws[wk][wn] = W[(k0 + wk) * F_HID + wn];
        }
        __syncthreads();
#pragma unroll
        for (int k = 0; k < 16; ++k) {
            float a[8];
            float b[4];
#pragma unroll
            for (int i = 0; i < 8; ++i) a[i] = Xs[k][ty * 8 + i];
#pragma unroll
            for (int j = 0; j < 4; ++j) b[j] = Ws[k][tx * 4 + j];
#pragma unroll
            for (int i = 0; i < 8; ++i) {
#pragma unroll
                for (int j = 0; j < 4; ++j) acc[i][j] += a[i] * b[j];
            }
        }
        __syncthreads();
    }
#pragma unroll
    for (int i = 0; i < 8; ++i) {
        int m = m0 + ty * 8 + i;
        if (m < N_NODES) {
            float4 o;
            o.x = acc[i][0]; o.y = acc[i][1]; o.z = acc[i][2]; o.w = acc[i][3];
            *(float4*)(h1 + (long long)m * F_HID + tx * 4) = o;
        }
    }
}

// ---- agg1 CSR: one wave per dst node, lane owns 2 features (float2).
// r1[d] = relu(dinv[d] * sum_e dinv[s]*h1[s] + dinv[d]^2 * h1[d] + b1). No atomics. ----
__global__ void g7_agg1(const int* rowptr, const int* csr, const float* dinv,
                        const float* h1, const float* b1, float* r1) {
    int node = blockIdx.x * 4 + (threadIdx.x >> 6);
    int lane = threadIdx.x & 63;
    if (node < N_NODES) {
        int beg = rowptr[node];
        int end = rowptr[node + 1];
        const float2* hv = (const float2*)h1;
        float ax = 0.0f;
        float ay = 0.0f;
        for (int j = beg; j < end; j = j + 1) {
            int s = csr[j];
            float w = dinv[s];
            float2 v = hv[(long long)s * 64 + lane];
            ax = ax + v.x * w;
            ay = ay + v.y * w;
        }
        float di = dinv[node];
        float2 hd = hv[(long long)node * 64 + lane];
        float rx = ax * di + hd.x * di * di + b1[2 * lane];
        float ry = ay * di + hd.y * di * di + b1[2 * lane + 1];
        if (rx < 0.0f) rx = 0.0f;
        if (ry < 0.0f) ry = 0.0f;
        float2 o;
        o.x = rx;
        o.y = ry;
        ((float2*)r1)[(long long)node * 64 + lane] = o;
    }
}

// ---- GEMM2: h2[100000,64] = r1 @ W2f. BM=64, BN=64, BK=32, 256 thr, 4x4 micro ----
__global__ void g7_gemm2(const float* r1, const float* W2, float* h2) {
    __shared__ float Rs[32][68];
    __shared__ float Ws[32][64];
    int tid = threadIdx.x;
    int m0 = blockIdx.x * 64;
    int tx = tid & 15;
    int ty = tid >> 4;
    float acc[4][4];
#pragma unroll
    for (int i = 0; i < 4; ++i) {
#pragma unroll
        for (int j = 0; j < 4; ++j) acc[i][j] = 0.0f;
    }

    for (int k0 = 0; k0 < F_HID; k0 += 32) {
#pragma unroll
        for (int r = 0; r < 8; ++r) {
            int i = r * 256 + tid;
            int kk = i & 31;
            int mm = i >> 5;
            int m = m0 + mm;
            float v = 0.0f;
            if (m < N_NODES) {
                v = r1[(long long)m * F_HID + k0 + kk];
            }
            Rs[kk][mm] = v;
        }
#pragma unroll
        for (int r = 0; r < 8; ++r) {
            int i = r * 256 + tid;
            int wk = i >> 6;
            int wn = i & 63;
            Ws[wk][wn] = W2[(k0 + wk) * F_OUT + wn];
        }
        __syncthreads();
#pragma unroll
        for (int k = 0; k < 32; ++k) {
            float a[4];
            float b[4];
#pragma unroll
            for (int i = 0; i < 4; ++i) a[i] = Rs[k][ty * 4 + i];
#pragma unroll
            for (int j = 0; j < 4; ++j) b[j] = Ws[k][tx * 4 + j];
#pragma unroll
            for (int i = 0; i < 4; ++i) {
#pragma unroll
                for (int j = 0; j < 4; ++j) acc[i][j] += a[i] * b[j];
            }
        }
        __syncthreads();
    }
#pragma unroll
    for (int i = 0; i < 4; ++i) {
        int m = m0 + ty * 4 + i;
        if (m < N_NODES) {
            float4 o;
            o.x = acc[i][0]; o.y = acc[i][1]; o.z = acc[i][2]; o.w = acc[i][3];
            *(float4*)(h2 + (long long)m * F_OUT + tx * 4) = o;
        }
    }
}

// ---- agg2 CSR + final epilogue fused: one wave per node, lane owns 1 feature.
// out[d] = dinv[d]*sum dinv[s]*h2[s] + dinv[d]^2*h2[d] + b2, in input float format ----
__global__ void g7_agg2(const int* rowptr, const int* csr, const float* dinv,
                        const float* h2, const float* b2, const int* fflag,
                        void* out) {
    int node = blockIdx.x * 4 + (threadIdx.x >> 6);
    int lane = threadIdx.x & 63;
    if (node < N_NODES) {
        int beg = rowptr[node];
        int end = rowptr[node + 1];
        float acc = 0.0f;
        for (int j = beg; j < end; j = j + 1) {
            int s = csr[j];
            acc = acc + h2[(long long)s * 64 + lane] * dinv[s];
        }
        float di = dinv[node];
        float v = acc * di + h2[(long long)node * 64 + lane] * di * di + b2[lane];
        long long oi = (long long)node * 64 + lane;
        if (fflag[0] == 1) {
            ((unsigned short*)out)[oi] = g7_f2bf(v);
        } else {
            ((float*)out)[oi] = v;
        }
    }
}

extern "C" void kernel_launch(void* const* d_in, const int* in_sizes, int n_in,
                              void* d_out, int out_size, void* d_ws, size_t ws_size,
                              hipStream_t stream) {
    const void* x     = d_in[0];
    const int* ei_raw = (const int*)d_in[1];
    const void* W1    = d_in[2];
    const void* b1    = d_in[3];
    const void* W2    = d_in[4];
    const void* b2    = d_in[5];

    const int NBLK = (N_NODES + 255) / 256;   // 391

    // workspace layout (byte offsets, 16B-aligned), end ~151.2 MB:
    char* ws = (char*)d_ws;
    int*   deg    = (int*)(ws + 0);            //    400,000 B
    int*   iflag  = (int*)(ws + 409600);       //          4 B
    int*   fflag  = (int*)(ws + 409616);       //          4 B
    int*   bsum   = (int*)(ws + 409632);       //      1,564 B
    int*   boff   = (int*)(ws + 412800);       //      1,564 B
    float* dinv   = (float*)(ws + 524288);     //    400,000 B
    float* W1f    = (float*)(ws + 1048576);    //    262,144 B
    float* b1f    = (float*)(ws + 1310720);    //        512 B
    float* W2f    = (float*)(ws + 1311232);    //     32,768 B
    float* b2f    = (float*)(ws + 1344000);    //        256 B
    unsigned short* W1T = (unsigned short*)(ws + 1572864); // 131,072 B
    int*   ei     = (int*)(ws + 2097152);      // 12,800,000 B
    int*   rowptr = (int*)(ws + 14897152);     //    400,004 B
    int*   cursor = (int*)(ws + 15298560);     //    400,000 B
    int*   csr    = (int*)(ws + 16777216);     //  6,400,000 B
    float* h1     = (float*)(ws + 23177216);   // 51,200,000 B
    float* r1     = (float*)(ws + 74377216);   // 51,200,000 B
    float* h2     = (float*)(ws + 125577216);  // 25,600,000 B

    g7_zero<<<(N_NODES + 255) / 256, 256, 0, stream>>>(deg, N_NODES);

    g7_iprobe<<<1, 64, 0, stream>>>(ei_raw, iflag);
    g7_fprobe<<<1, 64, 0, stream>>>((const unsigned int*)x, fflag);

    g7_pack<<<(2 * N_EDGES + 255) / 256, 256, 0, stream>>>(ei_raw, iflag, ei);

    g7_cvt<<<(F_IN * F_HID + 255) / 256, 256, 0, stream>>>(W1, fflag, W1f, F_IN * F_HID);
    g7_cvt<<<1, 128, 0, stream>>>(b1, fflag, b1f, F_HID);
    g7_cvt<<<(F_HID * F_OUT + 255) / 256, 256, 0, stream>>>(W2, fflag, W2f, F_HID * F_OUT);
    g7_cvt<<<1, 64, 0, stream>>>(b2, fflag, b2f, F_OUT);
    g7_w1t<<<(F_IN * F_HID + 255) / 256, 256, 0, stream>>>(W1, fflag, W1T);

    g7_deg<<<(N_EDGES + 255) / 256, 256, 0, stream>>>(ei, deg);
    g7_dinv<<<(N_NODES + 255) / 256, 256, 0, stream>>>(deg, dinv);

    // CSR build
    g7_bsum<<<NBLK, 256, 0, stream>>>(deg, bsum);
    g7_bscan<<<1, 64, 0, stream>>>(bsum, boff, NBLK, rowptr);
    g7_scan<<<NBLK, 256, 0, stream>>>(deg, boff, rowptr, cursor);
    g7_scatter<<<(N_EDGES + 255) / 256, 256, 0, stream>>>(ei, cursor, csr);

    // GEMM1: MFMA bf16 path + fp32 fallback (each early-exits on fflag)
    g7_gemm1m<<<(N_NODES + 127) / 128, 256, 0, stream>>>(x, fflag, W1T, h1);
    g7_gemm1<<<(N_NODES + 63) / 64, 256, 0, stream>>>(x, fflag, W1f, h1);

    g7_agg1<<<N_NODES / 4, 256, 0, stream>>>(rowptr, csr, dinv, h1, b1f, r1);

    g7_gemm2<<<(N_NODES + 63) / 64, 256, 0, stream>>>(r1, W2f, h2);

    g7_agg2<<<N_NODES / 4, 256, 0, stream>>>(rowptr, csr, dinv, h2, b2f, fflag, d_out);
}

// Round 2
// 1152.328 us; speedup vs baseline: 1.1146x; 1.1146x over previous
//
#include <hip/hip_runtime.h>

#define N_NODES 100000
#define N_EDGES 1600000
#define F_IN 512
#define F_HID 128
#define F_OUT 64

typedef unsigned int u32;
typedef __attribute__((ext_vector_type(8))) short bf16x8;
typedef __attribute__((ext_vector_type(4))) float f32x4;

__device__ float g7_bf2f(unsigned short u) {
    return __uint_as_float(((unsigned int)u) << 16);
}

__device__ unsigned short g7_f2bf(float f) {
    unsigned int u = __float_as_uint(f);
    u = u + 0x7fffu + ((u >> 16) & 1u);
    return (unsigned short)(u >> 16);
}

__device__ static inline void g7_gl2lds16(const void* g, void* l) {
    __builtin_amdgcn_global_load_lds(
        (const __attribute__((address_space(1))) u32*)g,
        (__attribute__((address_space(3))) u32*)l, 16, 0, 0);
}

__global__ void GCN_16716012716713_kernel() {}

__global__ void g7_zero(int* p, int n) {
    int i = blockIdx.x * blockDim.x + threadIdx.x;
    if (i < n) p[i] = 0;
}

// edge_index dtype probe: 1=int32, 0=int64 (int64 has all-zero high words)
__global__ void g7_iprobe(const int* raw, int* iflag) {
    if (blockIdx.x == 0 && threadIdx.x == 0) {
        int f = 0;
        for (int i = 0; i < 1024; i = i + 1) {
            if (raw[2 * i + 1] != 0) f = 1;
        }
        iflag[0] = f;
    }
}

// float dtype probe on x: 1=bf16, 0=fp32
__global__ void g7_fprobe(const unsigned int* xw, int* fflag) {
    if (blockIdx.x == 0 && threadIdx.x == 0) {
        int cnt = 0;
        for (int i = 0; i < 4096; i = i + 1) {
            unsigned int lo = xw[i] & 0xffffu;
            unsigned int e = (lo >> 7) & 0xffu;
            if (e >= 110u && e <= 140u) cnt = cnt + 1;
        }
        fflag[0] = (cnt > 2048) ? 1 : 0;
    }
}

__global__ void g7_pack(const int* raw, const int* iflag, int* ei) {
    int i = blockIdx.x * blockDim.x + threadIdx.x;
    if (i < 2 * N_EDGES) {
        if (iflag[0] == 0) {
            ei[i] = raw[2 * i];
        } else {
            ei[i] = raw[i];
        }
    }
}

__global__ void g7_cvt(const void* src, const int* fflag, float* dst, int n) {
    int i = blockIdx.x * blockDim.x + threadIdx.x;
    if (i < n) {
        if (fflag[0] == 1) {
            dst[i] = g7_bf2f(((const unsigned short*)src)[i]);
        } else {
            dst[i] = ((const float*)src)[i];
        }
    }
}

// W1T split: W1Th[n][k] = bf16_hi(W1[k][n]), W1Tl[n][k] = bf16(W1 - hi).
__global__ void g7_w1s(const void* W1, const int* fflag,
                       unsigned short* W1Th, unsigned short* W1Tl) {
    int i = blockIdx.x * blockDim.x + threadIdx.x;
    if (i < F_IN * F_HID) {
        int k = i >> 7;
        int n = i & 127;
        float w;
        if (fflag[0] == 1) {
            w = g7_bf2f(((const unsigned short*)W1)[i]);
        } else {
            w = ((const float*)W1)[i];
        }
        unsigned short hi = g7_f2bf(w);
        unsigned short lo = g7_f2bf(w - g7_bf2f(hi));
        W1Th[n * F_IN + k] = hi;
        W1Tl[n * F_IN + k] = lo;
    }
}

__global__ void g7_deg(const int* ei, int* deg) {
    int e = blockIdx.x * blockDim.x + threadIdx.x;
    if (e < N_EDGES) {
        atomicAdd(&deg[ei[N_EDGES + e]], 1);
    }
}

__global__ void g7_dinv(const int* deg, float* dinv) {
    int i = blockIdx.x * blockDim.x + threadIdx.x;
    if (i < N_NODES) {
        dinv[i] = rsqrtf((float)deg[i] + 1.0f);
    }
}

// ---- CSR build: block-sums -> serial scan of 391 block sums -> per-block scan ----
__global__ void g7_bsum(const int* deg, int* bsum) {
    __shared__ int s[256];
    int i = blockIdx.x * 256 + threadIdx.x;
    s[threadIdx.x] = (i < N_NODES) ? deg[i] : 0;
    __syncthreads();
    for (int off = 128; off > 0; off >>= 1) {
        if (threadIdx.x < off) s[threadIdx.x] += s[threadIdx.x + off];
        __syncthreads();
    }
    if (threadIdx.x == 0) bsum[blockIdx.x] = s[0];
}

__global__ void g7_bscan(const int* bsum, int* boff, int nblk, int* rowptr) {
    if (blockIdx.x == 0 && threadIdx.x == 0) {
        int acc = 0;
        for (int b = 0; b < nblk; b = b + 1) {
            boff[b] = acc;
            acc = acc + bsum[b];
        }
        rowptr[N_NODES] = acc;   // == N_EDGES
    }
}

__global__ void g7_scan(const int* deg, const int* boff, int* rowptr, int* cursor) {
    __shared__ int s[256];
    int i = blockIdx.x * 256 + threadIdx.x;
    int v = (i < N_NODES) ? deg[i] : 0;
    s[threadIdx.x] = v;
    __syncthreads();
    for (int off = 1; off < 256; off <<= 1) {
        int t = (threadIdx.x >= off) ? s[threadIdx.x - off] : 0;
        __syncthreads();
        s[threadIdx.x] += t;
        __syncthreads();
    }
    if (i < N_NODES) {
        int excl = s[threadIdx.x] - v + boff[blockIdx.x];
        rowptr[i] = excl;
        cursor[i] = excl;
    }
}

// scatter src ids into dst-grouped CSR order
__global__ void g7_scatter(const int* ei, int* cursor, int* csr) {
    int e = blockIdx.x * blockDim.x + threadIdx.x;
    if (e < N_EDGES) {
        int s = ei[e];
        int d = ei[N_EDGES + e];
        int pos = atomicAdd(&cursor[d], 1);
        csr[pos] = s;
    }
}

// ---- GEMM1 split-bf16 MFMA: h1[100000,128] = x @ W1, fp32-class accuracy.
// x_hi+x_lo (bf16), W_hi+W_lo (bf16); acc = xh*Wh + xl*Wh + xh*Wl in fp32.
// BM=128, BN=128, BK=32, 256 thr = 4 waves (2x2), wave = 64x64 out.
// LDS rows 128B = [hi 64B | lo 64B], XOR-swizzle ((r&7)<<4); A reg-staged
// (issue-early/convert-late), B via global_load_lds w/ pre-swizzled source. ----
__global__ __launch_bounds__(256, 2) void g7_gemm1s(const void* x, const int* fflag,
        const unsigned short* W1Th, const unsigned short* W1Tl, float* h1) {
    __shared__ uint4 smv[4096];          // 64 KB: 2 x (A 16K + B 16K)
    char* smc = (char*)smv;
    int tid = threadIdx.x;
    int m0 = blockIdx.x * 128;
    int w = tid >> 6;
    int lane = tid & 63;
    int wr = w >> 1, wc = w & 1;         // wave grid 2x2
    int la = lane & 15;                  // mfma row/col within 16
    int lk = lane >> 4;                  // mfma k-group (8 bf16 = 16 B)
    int isbf = fflag[0];
    int ar = tid >> 1;                   // A staging: row
    int ah = tid & 1;                    // A staging: k-half (16 elems)

    f32x4 acc[4][4];
#pragma unroll
    for (int i = 0; i < 4; ++i)
#pragma unroll
        for (int j = 0; j < 4; ++j) acc[i][j] = (f32x4){0.f, 0.f, 0.f, 0.f};

    uint4 rA[4];

    // issue A-tile global loads (16 fp32 or 16 bf16 per thread), no wait
    auto loadA = [&](int k0) {
        int m = m0 + ar;
        if (m >= N_NODES) m = N_NODES - 1;   // dup-read, discarded at store
        if (isbf) {
            const char* s = (const char*)x + ((long long)m * F_IN + k0 + ah * 16) * 2;
            rA[0] = *(const uint4*)s;
            rA[1] = *(const uint4*)(s + 16);
        } else {
            const char* s = (const char*)x + ((long long)m * F_IN + k0 + ah * 16) * 4;
            rA[0] = *(const uint4*)s;
            rA[1] = *(const uint4*)(s + 16);
            rA[2] = *(const uint4*)(s + 32);
            rA[3] = *(const uint4*)(s + 48);
        }
    };

    // convert regs -> hi/lo bf16, swizzled ds_write (called AFTER compute)
    auto writeA = [&](char* As) {
        float f[16];
        if (isbf) {
            const unsigned short* p = (const unsigned short*)rA;
#pragma unroll
            for (int j = 0; j < 16; ++j) f[j] = g7_bf2f(p[j]);
        } else {
            const float* p = (const float*)rA;
#pragma unroll
            for (int j = 0; j < 16; ++j) f[j] = p[j];
        }
        unsigned int hw[8], lw[8];
#pragma unroll
        for (int j = 0; j < 8; ++j) {
            unsigned short h0 = g7_f2bf(f[2 * j]);
            unsigned short h1v = g7_f2bf(f[2 * j + 1]);
            unsigned short l0 = g7_f2bf(f[2 * j] - g7_bf2f(h0));
            unsigned short l1 = g7_f2bf(f[2 * j + 1] - g7_bf2f(h1v));
            hw[j] = (unsigned int)h0 | ((unsigned int)h1v << 16);
            lw[j] = (unsigned int)l0 | ((unsigned int)l1 << 16);
        }
        int swz = (ar & 7) << 4;
        char* dst = As + ar * 128;
        *(uint4*)(dst + ((ah * 32 + 0) ^ swz))      = make_uint4(hw[0], hw[1], hw[2], hw[3]);
        *(uint4*)(dst + ((ah * 32 + 16) ^ swz))     = make_uint4(hw[4], hw[5], hw[6], hw[7]);
        *(uint4*)(dst + ((64 + ah * 32 + 0) ^ swz)) = make_uint4(lw[0], lw[1], lw[2], lw[3]);
        *(uint4*)(dst + ((64 + ah * 32 + 16) ^ swz))= make_uint4(lw[4], lw[5], lw[6], lw[7]);
    };

    // B-tile: rows n 0..127, 128B = [hi|lo], linear LDS dest + inverse-swizzled source
    auto stageB = [&](char* Bs, int k0) {
#pragma unroll
        for (int p = 0; p < 4; ++p) {
            int nr = w * 32 + p * 8 + (lane >> 3);
            int cp = ((lane & 7) * 16) ^ (((lane >> 3) & 7) << 4);  // source col in [0,128)
            const char* src = (cp < 64)
                ? (const char*)W1Th + (long long)nr * 1024 + k0 * 2 + cp
                : (const char*)W1Tl + (long long)nr * 1024 + k0 * 2 + (cp - 64);
            g7_gl2lds16(src, Bs + (w * 32 + p * 8) * 128);
        }
    };

    auto compute = [&](const char* As, const char* Bs) {
        bf16x8 a_hi[4], a_lo[4], b_hi[4], b_lo[4];
#pragma unroll
        for (int i = 0; i < 4; ++i) {
            int r = wr * 64 + i * 16 + la;
            int swz = (r & 7) << 4;
            const char* ab = As + r * 128;
            a_hi[i] = *(const bf16x8*)(ab + ((lk * 16) ^ swz));
            a_lo[i] = *(const bf16x8*)(ab + ((64 + lk * 16) ^ swz));
            int n = wc * 64 + i * 16 + la;
            int swzb = (n & 7) << 4;
            const char* bb = Bs + n * 128;
            b_hi[i] = *(const bf16x8*)(bb + ((lk * 16) ^ swzb));
            b_lo[i] = *(const bf16x8*)(bb + ((64 + lk * 16) ^ swzb));
        }
#pragma unroll
        for (int i = 0; i < 4; ++i)
#pragma unroll
            for (int j = 0; j < 4; ++j) {
                acc[i][j] = __builtin_amdgcn_mfma_f32_16x16x32_bf16(
                    a_hi[i], b_hi[j], acc[i][j], 0, 0, 0);
                acc[i][j] = __builtin_amdgcn_mfma_f32_16x16x32_bf16(
                    a_lo[i], b_hi[j], acc[i][j], 0, 0, 0);
                acc[i][j] = __builtin_amdgcn_mfma_f32_16x16x32_bf16(
                    a_hi[i], b_lo[j], acc[i][j], 0, 0, 0);
            }
    };

    // prologue: stage K-step 0 into buffer 0
    loadA(0);
    stageB(smc + 16384, 0);
    writeA(smc);
    __syncthreads();                      // drains vmcnt: buf0 ready

    for (int kt = 0; kt < 16; ++kt) {
        char* bc = smc + (kt & 1) * 32768;
        char* bn = smc + ((kt & 1) ^ 1) * 32768;
        if (kt < 15) {                    // issue next-tile loads early (T14)
            loadA((kt + 1) * 32);
            stageB(bn + 16384, (kt + 1) * 32);
        }
        compute(bc, bc + 16384);
        if (kt < 15) writeA(bn);          // convert-late: vmcnt wait lands here
        __syncthreads();
    }

    // epilogue: D row = lk*4+q (m), col = la (n) per 16x16 fragment
#pragma unroll
    for (int i = 0; i < 4; ++i) {
#pragma unroll
        for (int j = 0; j < 4; ++j) {
            int n = wc * 64 + j * 16 + la;
#pragma unroll
            for (int q = 0; q < 4; ++q) {
                int m = m0 + wr * 64 + i * 16 + lk * 4 + q;
                if (m < N_NODES) {
                    h1[(long long)m * F_HID + n] = acc[i][j][q];
                }
            }
        }
    }
}

// ---- agg1 CSR: one wave per dst node, lane owns 2 features (float2).
// r1[d] = relu(dinv[d] * sum_e dinv[s]*h1[s] + dinv[d]^2 * h1[d] + b1). No atomics. ----
__global__ void g7_agg1(const int* rowptr, const int* csr, const float* dinv,
                        const float* h1, const float* b1, float* r1) {
    int node = blockIdx.x * 4 + (threadIdx.x >> 6);
    int lane = threadIdx.x & 63;
    if (node < N_NODES) {
        int beg = rowptr[node];
        int end = rowptr[node + 1];
        const float2* hv = (const float2*)h1;
        float ax = 0.0f;
        float ay = 0.0f;
        for (int j = beg; j < end; j = j + 1) {
            int s = csr[j];
            float w = dinv[s];
            float2 v = hv[(long long)s * 64 + lane];
            ax = ax + v.x * w;
            ay = ay + v.y * w;
        }
        float di = dinv[node];
        float2 hd = hv[(long long)node * 64 + lane];
        float rx = ax * di + hd.x * di * di + b1[2 * lane];
        float ry = ay * di + hd.y * di * di + b1[2 * lane + 1];
        if (rx < 0.0f) rx = 0.0f;
        if (ry < 0.0f) ry = 0.0f;
        float2 o;
        o.x = rx;
        o.y = ry;
        ((float2*)r1)[(long long)node * 64 + lane] = o;
    }
}

// ---- GEMM2: h2[100000,64] = r1 @ W2f. BM=64, BN=64, BK=32, 256 thr, 4x4 micro ----
__global__ void g7_gemm2(const float* r1, const float* W2, float* h2) {
    __shared__ float Rs[32][68];
    __shared__ float Ws[32][64];
    int tid = threadIdx.x;
    int m0 = blockIdx.x * 64;
    int tx = tid & 15;
    int ty = tid >> 4;
    float acc[4][4];
#pragma unroll
    for (int i = 0; i < 4; ++i) {
#pragma unroll
        for (int j = 0; j < 4; ++j) acc[i][j] = 0.0f;
    }

    for (int k0 = 0; k0 < F_HID; k0 += 32) {
#pragma unroll
        for (int r = 0; r < 8; ++r) {
            int i = r * 256 + tid;
            int kk = i & 31;
            int mm = i >> 5;
            int m = m0 + mm;
            float v = 0.0f;
            if (m < N_NODES) {
                v = r1[(long long)m * F_HID + k0 + kk];
            }
            Rs[kk][mm] = v;
        }
#pragma unroll
        for (int r = 0; r < 8; ++r) {
            int i = r * 256 + tid;
            int wk = i >> 6;
            int wn = i & 63;
            Ws[wk][wn] = W2[(k0 + wk) * F_OUT + wn];
        }
        __syncthreads();
#pragma unroll
        for (int k = 0; k < 32; ++k) {
            float a[4];
            float b[4];
#pragma unroll
            for (int i = 0; i < 4; ++i) a[i] = Rs[k][ty * 4 + i];
#pragma unroll
            for (int j = 0; j < 4; ++j) b[j] = Ws[k][tx * 4 + j];
#pragma unroll
            for (int i = 0; i < 4; ++i) {
#pragma unroll
                for (int j = 0; j < 4; ++j) acc[i][j] += a[i] * b[j];
            }
        }
        __syncthreads();
    }
#pragma unroll
    for (int i = 0; i < 4; ++i) {
        int m = m0 + ty * 4 + i;
        if (m < N_NODES) {
            float4 o;
            o.x = acc[i][0]; o.y = acc[i][1]; o.z = acc[i][2]; o.w = acc[i][3];
            *(float4*)(h2 + (long long)m * F_OUT + tx * 4) = o;
        }
    }
}

// ---- agg2 CSR + final epilogue fused: one wave per node, lane owns 1 feature.
// out[d] = dinv[d]*sum dinv[s]*h2[s] + dinv[d]^2*h2[d] + b2, in input float format ----
__global__ void g7_agg2(const int* rowptr, const int* csr, const float* dinv,
                        const float* h2, const float* b2, const int* fflag,
                        void* out) {
    int node = blockIdx.x * 4 + (threadIdx.x >> 6);
    int lane = threadIdx.x & 63;
    if (node < N_NODES) {
        int beg = rowptr[node];
        int end = rowptr[node + 1];
        float acc = 0.0f;
        for (int j = beg; j < end; j = j + 1) {
            int s = csr[j];
            acc = acc + h2[(long long)s * 64 + lane] * dinv[s];
        }
        float di = dinv[node];
        float v = acc * di + h2[(long long)node * 64 + lane] * di * di + b2[lane];
        long long oi = (long long)node * 64 + lane;
        if (fflag[0] == 1) {
            ((unsigned short*)out)[oi] = g7_f2bf(v);
        } else {
            ((float*)out)[oi] = v;
        }
    }
}

extern "C" void kernel_launch(void* const* d_in, const int* in_sizes, int n_in,
                              void* d_out, int out_size, void* d_ws, size_t ws_size,
                              hipStream_t stream) {
    const void* x     = d_in[0];
    const int* ei_raw = (const int*)d_in[1];
    const void* W1    = d_in[2];
    const void* b1    = d_in[3];
    const void* W2    = d_in[4];
    const void* b2    = d_in[5];

    const int NBLK = (N_NODES + 255) / 256;   // 391

    // workspace layout (byte offsets, 16B-aligned), end ~151.2 MB:
    char* ws = (char*)d_ws;
    int*   deg    = (int*)(ws + 0);            //    400,000 B
    int*   iflag  = (int*)(ws + 409600);       //          4 B
    int*   fflag  = (int*)(ws + 409616);       //          4 B
    int*   bsum   = (int*)(ws + 409632);       //      1,564 B
    int*   boff   = (int*)(ws + 412800);       //      1,564 B
    float* dinv   = (float*)(ws + 524288);     //    400,000 B
    unsigned short* W1Th = (unsigned short*)(ws + 1048576); // 131,072 B
    unsigned short* W1Tl = (unsigned short*)(ws + 1179648); // 131,072 B
    float* b1f    = (float*)(ws + 1310720);    //        512 B
    float* W2f    = (float*)(ws + 1311232);    //     32,768 B
    float* b2f    = (float*)(ws + 1344000);    //        256 B
    int*   ei     = (int*)(ws + 2097152);      // 12,800,000 B
    int*   rowptr = (int*)(ws + 14897152);     //    400,004 B
    int*   cursor = (int*)(ws + 15298560);     //    400,000 B
    int*   csr    = (int*)(ws + 16777216);     //  6,400,000 B
    float* h1     = (float*)(ws + 23177216);   // 51,200,000 B
    float* r1     = (float*)(ws + 74377216);   // 51,200,000 B
    float* h2     = (float*)(ws + 125577216);  // 25,600,000 B

    g7_zero<<<(N_NODES + 255) / 256, 256, 0, stream>>>(deg, N_NODES);

    g7_iprobe<<<1, 64, 0, stream>>>(ei_raw, iflag);
    g7_fprobe<<<1, 64, 0, stream>>>((const unsigned int*)x, fflag);

    g7_pack<<<(2 * N_EDGES + 255) / 256, 256, 0, stream>>>(ei_raw, iflag, ei);

    g7_cvt<<<1, 128, 0, stream>>>(b1, fflag, b1f, F_HID);
    g7_cvt<<<(F_HID * F_OUT + 255) / 256, 256, 0, stream>>>(W2, fflag, W2f, F_HID * F_OUT);
    g7_cvt<<<1, 64, 0, stream>>>(b2, fflag, b2f, F_OUT);
    g7_w1s<<<(F_IN * F_HID + 255) / 256, 256, 0, stream>>>(W1, fflag, W1Th, W1Tl);

    g7_deg<<<(N_EDGES + 255) / 256, 256, 0, stream>>>(ei, deg);
    g7_dinv<<<(N_NODES + 255) / 256, 256, 0, stream>>>(deg, dinv);

    // CSR build
    g7_bsum<<<NBLK, 256, 0, stream>>>(deg, bsum);
    g7_bscan<<<1, 64, 0, stream>>>(bsum, boff, NBLK, rowptr);
    g7_scan<<<NBLK, 256, 0, stream>>>(deg, boff, rowptr, cursor);
    g7_scatter<<<(N_EDGES + 255) / 256, 256, 0, stream>>>(ei, cursor, csr);

    // GEMM1: split-bf16 MFMA (fp32-class accuracy), handles both input dtypes
    g7_gemm1s<<<(N_NODES + 127) / 128, 256, 0, stream>>>(x, fflag, W1Th, W1Tl, h1);

    g7_agg1<<<N_NODES / 4, 256, 0, stream>>>(rowptr, csr, dinv, h1, b1f, r1);

    g7_gemm2<<<(N_NODES + 63) / 64, 256, 0, stream>>>(r1, W2f, h2);

    g7_agg2<<<N_NODES / 4, 256, 0, stream>>>(rowptr, csr, dinv, h2, b2f, fflag, d_out);
}

// Round 3
// 969.196 us; speedup vs baseline: 1.3252x; 1.1890x over previous
//
#include <hip/hip_runtime.h>

#define N_NODES 100000
#define N_EDGES 1600000
#define F_IN 512
#define F_HID 128
#define F_OUT 64

typedef unsigned int u32;
typedef __attribute__((ext_vector_type(8))) short bf16x8;
typedef __attribute__((ext_vector_type(4))) float f32x4;

__device__ float g7_bf2f(unsigned short u) {
    return __uint_as_float(((unsigned int)u) << 16);
}

__device__ unsigned short g7_f2bf(float f) {
    unsigned int u = __float_as_uint(f);
    u = u + 0x7fffu + ((u >> 16) & 1u);
    return (unsigned short)(u >> 16);
}

// unpack a u32 of 2 packed bf16 -> (lo, hi) floats
__device__ float2 g7_up(unsigned int u) {
    float2 r;
    r.x = __uint_as_float(u << 16);
    r.y = __uint_as_float(u & 0xffff0000u);
    return r;
}

__device__ static inline void g7_gl2lds16(const void* g, void* l) {
    __builtin_amdgcn_global_load_lds(
        (const __attribute__((address_space(1))) u32*)g,
        (__attribute__((address_space(3))) u32*)l, 16, 0, 0);
}

__global__ void GCN_16716012716713_kernel() {}

__global__ void g7_zero(int* p, int n) {
    int i = blockIdx.x * blockDim.x + threadIdx.x;
    if (i < n) p[i] = 0;
}

// edge_index dtype probe: 1=int32, 0=int64 (int64 has all-zero high words)
__global__ void g7_iprobe(const int* raw, int* iflag) {
    if (blockIdx.x == 0 && threadIdx.x == 0) {
        int f = 0;
        for (int i = 0; i < 1024; i = i + 1) {
            if (raw[2 * i + 1] != 0) f = 1;
        }
        iflag[0] = f;
    }
}

// float dtype probe on x: 1=bf16, 0=fp32
__global__ void g7_fprobe(const unsigned int* xw, int* fflag) {
    if (blockIdx.x == 0 && threadIdx.x == 0) {
        int cnt = 0;
        for (int i = 0; i < 4096; i = i + 1) {
            unsigned int lo = xw[i] & 0xffffu;
            unsigned int e = (lo >> 7) & 0xffu;
            if (e >= 110u && e <= 140u) cnt = cnt + 1;
        }
        fflag[0] = (cnt > 2048) ? 1 : 0;
    }
}

__global__ void g7_pack(const int* raw, const int* iflag, int* ei) {
    int i = blockIdx.x * blockDim.x + threadIdx.x;
    if (i < 2 * N_EDGES) {
        if (iflag[0] == 0) {
            ei[i] = raw[2 * i];
        } else {
            ei[i] = raw[i];
        }
    }
}

__global__ void g7_cvt(const void* src, const int* fflag, float* dst, int n) {
    int i = blockIdx.x * blockDim.x + threadIdx.x;
    if (i < n) {
        if (fflag[0] == 1) {
            dst[i] = g7_bf2f(((const unsigned short*)src)[i]);
        } else {
            dst[i] = ((const float*)src)[i];
        }
    }
}

// W1T split: W1Th[n][k] = bf16_hi(W1[k][n]), W1Tl[n][k] = bf16(W1 - hi).
__global__ void g7_w1s(const void* W1, const int* fflag,
                       unsigned short* W1Th, unsigned short* W1Tl) {
    int i = blockIdx.x * blockDim.x + threadIdx.x;
    if (i < F_IN * F_HID) {
        int k = i >> 7;
        int n = i & 127;
        float w;
        if (fflag[0] == 1) {
            w = g7_bf2f(((const unsigned short*)W1)[i]);
        } else {
            w = ((const float*)W1)[i];
        }
        unsigned short hi = g7_f2bf(w);
        unsigned short lo = g7_f2bf(w - g7_bf2f(hi));
        W1Th[n * F_IN + k] = hi;
        W1Tl[n * F_IN + k] = lo;
    }
}

__global__ void g7_deg(const int* ei, int* deg) {
    int e = blockIdx.x * blockDim.x + threadIdx.x;
    if (e < N_EDGES) {
        atomicAdd(&deg[ei[N_EDGES + e]], 1);
    }
}

__global__ void g7_dinv(const int* deg, float* dinv) {
    int i = blockIdx.x * blockDim.x + threadIdx.x;
    if (i < N_NODES) {
        dinv[i] = rsqrtf((float)deg[i] + 1.0f);
    }
}

// ---- CSR build: block-sums -> serial scan of 391 block sums -> per-block scan ----
__global__ void g7_bsum(const int* deg, int* bsum) {
    __shared__ int s[256];
    int i = blockIdx.x * 256 + threadIdx.x;
    s[threadIdx.x] = (i < N_NODES) ? deg[i] : 0;
    __syncthreads();
    for (int off = 128; off > 0; off >>= 1) {
        if (threadIdx.x < off) s[threadIdx.x] += s[threadIdx.x + off];
        __syncthreads();
    }
    if (threadIdx.x == 0) bsum[blockIdx.x] = s[0];
}

__global__ void g7_bscan(const int* bsum, int* boff, int nblk, int* rowptr) {
    if (blockIdx.x == 0 && threadIdx.x == 0) {
        int acc = 0;
        for (int b = 0; b < nblk; b = b + 1) {
            boff[b] = acc;
            acc = acc + bsum[b];
        }
        rowptr[N_NODES] = acc;   // == N_EDGES
    }
}

__global__ void g7_scan(const int* deg, const int* boff, int* rowptr, int* cursor) {
    __shared__ int s[256];
    int i = blockIdx.x * 256 + threadIdx.x;
    int v = (i < N_NODES) ? deg[i] : 0;
    s[threadIdx.x] = v;
    __syncthreads();
    for (int off = 1; off < 256; off <<= 1) {
        int t = (threadIdx.x >= off) ? s[threadIdx.x - off] : 0;
        __syncthreads();
        s[threadIdx.x] += t;
        __syncthreads();
    }
    if (i < N_NODES) {
        int excl = s[threadIdx.x] - v + boff[blockIdx.x];
        rowptr[i] = excl;
        cursor[i] = excl;
    }
}

// scatter src ids into dst-grouped CSR order
__global__ void g7_scatter(const int* ei, int* cursor, int* csr) {
    int e = blockIdx.x * blockDim.x + threadIdx.x;
    if (e < N_EDGES) {
        int s = ei[e];
        int d = ei[N_EDGES + e];
        int pos = atomicAdd(&cursor[d], 1);
        csr[pos] = s;
    }
}

// ---- GEMM1 split-bf16 MFMA: h1[100000,128] = x @ W1, fp32-class accuracy.
// Output stored as bf16 (h1b) to halve agg1 gather traffic. ----
__global__ __launch_bounds__(256, 2) void g7_gemm1s(const void* x, const int* fflag,
        const unsigned short* W1Th, const unsigned short* W1Tl, unsigned short* h1b) {
    __shared__ uint4 smv[4096];          // 64 KB: 2 x (A 16K + B 16K)
    char* smc = (char*)smv;
    int tid = threadIdx.x;
    int m0 = blockIdx.x * 128;
    int w = tid >> 6;
    int lane = tid & 63;
    int wr = w >> 1, wc = w & 1;         // wave grid 2x2
    int la = lane & 15;                  // mfma row/col within 16
    int lk = lane >> 4;                  // mfma k-group (8 bf16 = 16 B)
    int isbf = fflag[0];
    int ar = tid >> 1;                   // A staging: row
    int ah = tid & 1;                    // A staging: k-half (16 elems)

    f32x4 acc[4][4];
#pragma unroll
    for (int i = 0; i < 4; ++i)
#pragma unroll
        for (int j = 0; j < 4; ++j) acc[i][j] = (f32x4){0.f, 0.f, 0.f, 0.f};

    uint4 rA[4];

    // issue A-tile global loads (16 fp32 or 16 bf16 per thread), no wait
    auto loadA = [&](int k0) {
        int m = m0 + ar;
        if (m >= N_NODES) m = N_NODES - 1;   // dup-read, discarded at store
        if (isbf) {
            const char* s = (const char*)x + ((long long)m * F_IN + k0 + ah * 16) * 2;
            rA[0] = *(const uint4*)s;
            rA[1] = *(const uint4*)(s + 16);
        } else {
            const char* s = (const char*)x + ((long long)m * F_IN + k0 + ah * 16) * 4;
            rA[0] = *(const uint4*)s;
            rA[1] = *(const uint4*)(s + 16);
            rA[2] = *(const uint4*)(s + 32);
            rA[3] = *(const uint4*)(s + 48);
        }
    };

    // convert regs -> hi/lo bf16, swizzled ds_write (called AFTER compute)
    auto writeA = [&](char* As) {
        float f[16];
        if (isbf) {
            const unsigned short* p = (const unsigned short*)rA;
#pragma unroll
            for (int j = 0; j < 16; ++j) f[j] = g7_bf2f(p[j]);
        } else {
            const float* p = (const float*)rA;
#pragma unroll
            for (int j = 0; j < 16; ++j) f[j] = p[j];
        }
        unsigned int hw[8], lw[8];
#pragma unroll
        for (int j = 0; j < 8; ++j) {
            unsigned short h0 = g7_f2bf(f[2 * j]);
            unsigned short h1v = g7_f2bf(f[2 * j + 1]);
            unsigned short l0 = g7_f2bf(f[2 * j] - g7_bf2f(h0));
            unsigned short l1 = g7_f2bf(f[2 * j + 1] - g7_bf2f(h1v));
            hw[j] = (unsigned int)h0 | ((unsigned int)h1v << 16);
            lw[j] = (unsigned int)l0 | ((unsigned int)l1 << 16);
        }
        int swz = (ar & 7) << 4;
        char* dst = As + ar * 128;
        *(uint4*)(dst + ((ah * 32 + 0) ^ swz))      = make_uint4(hw[0], hw[1], hw[2], hw[3]);
        *(uint4*)(dst + ((ah * 32 + 16) ^ swz))     = make_uint4(hw[4], hw[5], hw[6], hw[7]);
        *(uint4*)(dst + ((64 + ah * 32 + 0) ^ swz)) = make_uint4(lw[0], lw[1], lw[2], lw[3]);
        *(uint4*)(dst + ((64 + ah * 32 + 16) ^ swz))= make_uint4(lw[4], lw[5], lw[6], lw[7]);
    };

    // B-tile: rows n 0..127, 128B = [hi|lo], linear LDS dest + inverse-swizzled source
    auto stageB = [&](char* Bs, int k0) {
#pragma unroll
        for (int p = 0; p < 4; ++p) {
            int nr = w * 32 + p * 8 + (lane >> 3);
            int cp = ((lane & 7) * 16) ^ (((lane >> 3) & 7) << 4);  // source col in [0,128)
            const char* src = (cp < 64)
                ? (const char*)W1Th + (long long)nr * 1024 + k0 * 2 + cp
                : (const char*)W1Tl + (long long)nr * 1024 + k0 * 2 + (cp - 64);
            g7_gl2lds16(src, Bs + (w * 32 + p * 8) * 128);
        }
    };

    auto compute = [&](const char* As, const char* Bs) {
        bf16x8 a_hi[4], a_lo[4], b_hi[4], b_lo[4];
#pragma unroll
        for (int i = 0; i < 4; ++i) {
            int r = wr * 64 + i * 16 + la;
            int swz = (r & 7) << 4;
            const char* ab = As + r * 128;
            a_hi[i] = *(const bf16x8*)(ab + ((lk * 16) ^ swz));
            a_lo[i] = *(const bf16x8*)(ab + ((64 + lk * 16) ^ swz));
            int n = wc * 64 + i * 16 + la;
            int swzb = (n & 7) << 4;
            const char* bb = Bs + n * 128;
            b_hi[i] = *(const bf16x8*)(bb + ((lk * 16) ^ swzb));
            b_lo[i] = *(const bf16x8*)(bb + ((64 + lk * 16) ^ swzb));
        }
#pragma unroll
        for (int i = 0; i < 4; ++i)
#pragma unroll
            for (int j = 0; j < 4; ++j) {
                acc[i][j] = __builtin_amdgcn_mfma_f32_16x16x32_bf16(
                    a_hi[i], b_hi[j], acc[i][j], 0, 0, 0);
                acc[i][j] = __builtin_amdgcn_mfma_f32_16x16x32_bf16(
                    a_lo[i], b_hi[j], acc[i][j], 0, 0, 0);
                acc[i][j] = __builtin_amdgcn_mfma_f32_16x16x32_bf16(
                    a_hi[i], b_lo[j], acc[i][j], 0, 0, 0);
            }
    };

    // prologue: stage K-step 0 into buffer 0
    loadA(0);
    stageB(smc + 16384, 0);
    writeA(smc);
    __syncthreads();                      // drains vmcnt: buf0 ready

    for (int kt = 0; kt < 16; ++kt) {
        char* bc = smc + (kt & 1) * 32768;
        char* bn = smc + ((kt & 1) ^ 1) * 32768;
        if (kt < 15) {                    // issue next-tile loads early (T14)
            loadA((kt + 1) * 32);
            stageB(bn + 16384, (kt + 1) * 32);
        }
        compute(bc, bc + 16384);
        if (kt < 15) writeA(bn);          // convert-late: vmcnt wait lands here
        __syncthreads();
    }

    // epilogue: D row = lk*4+q (m), col = la (n) per 16x16 fragment; bf16 store
#pragma unroll
    for (int i = 0; i < 4; ++i) {
#pragma unroll
        for (int j = 0; j < 4; ++j) {
            int n = wc * 64 + j * 16 + la;
#pragma unroll
            for (int q = 0; q < 4; ++q) {
                int m = m0 + wr * 64 + i * 16 + lk * 4 + q;
                if (m < N_NODES) {
                    h1b[(long long)m * F_HID + n] = g7_f2bf(acc[i][j][q]);
                }
            }
        }
    }
}

// ---- agg1 CSR gather, bf16 table, dual-edge halves + 2-wide unroll (4 gathers in flight).
// Wave = 1 node. Halves (lanes 0-31 / 32-63) own alternating edges; lane fl owns
// features 4fl..4fl+3 (uint2 of 4 packed bf16). Self-loop folded as edge w=dinv[d].
// r1[d] = relu(dinv[d]*acc + b1), fp32. ----
__global__ void g7_agg1(const int* rowptr, const int* csr, const float* dinv,
                        const unsigned short* h1b, const float* b1, float* r1) {
    int node = blockIdx.x * 4 + (threadIdx.x >> 6);
    int lane = threadIdx.x & 63;
    int e = lane >> 5;
    int fl = lane & 31;
    if (node >= N_NODES) return;
    int beg = rowptr[node];
    int end = rowptr[node + 1];
    const uint2* hv = (const uint2*)h1b;   // row = 32 uint2
    float a0 = 0.f, a1 = 0.f, a2 = 0.f, a3 = 0.f;
    int j = beg + e;
    for (; j + 2 < end; j += 4) {
        int s0 = csr[j];
        int s1 = csr[j + 2];
        float w0 = dinv[s0];
        float w1 = dinv[s1];
        uint2 v0 = hv[(long long)s0 * 32 + fl];
        uint2 v1 = hv[(long long)s1 * 32 + fl];
        float2 p0 = g7_up(v0.x), q0 = g7_up(v0.y);
        float2 p1 = g7_up(v1.x), q1 = g7_up(v1.y);
        a0 += p0.x * w0 + p1.x * w1;
        a1 += p0.y * w0 + p1.y * w1;
        a2 += q0.x * w0 + q1.x * w1;
        a3 += q0.y * w0 + q1.y * w1;
    }
    if (j < end) {
        int s0 = csr[j];
        float w0 = dinv[s0];
        uint2 v0 = hv[(long long)s0 * 32 + fl];
        float2 p0 = g7_up(v0.x), q0 = g7_up(v0.y);
        a0 += p0.x * w0;
        a1 += p0.y * w0;
        a2 += q0.x * w0;
        a3 += q0.y * w0;
    }
    float di = dinv[node];
    if (e == 0) {                     // self-loop as an edge with w = dinv[node]
        uint2 vd = hv[(long long)node * 32 + fl];
        float2 pd = g7_up(vd.x), qd = g7_up(vd.y);
        a0 += pd.x * di;
        a1 += pd.y * di;
        a2 += qd.x * di;
        a3 += qd.y * di;
    }
    a0 += __shfl_xor(a0, 32);
    a1 += __shfl_xor(a1, 32);
    a2 += __shfl_xor(a2, 32);
    a3 += __shfl_xor(a3, 32);
    if (e == 0) {
        float4 bb = *(const float4*)(b1 + 4 * fl);
        float r0 = a0 * di + bb.x;
        float r1v = a1 * di + bb.y;
        float r2 = a2 * di + bb.z;
        float r3 = a3 * di + bb.w;
        if (r0 < 0.f) r0 = 0.f;
        if (r1v < 0.f) r1v = 0.f;
        if (r2 < 0.f) r2 = 0.f;
        if (r3 < 0.f) r3 = 0.f;
        float4 o;
        o.x = r0; o.y = r1v; o.z = r2; o.w = r3;
        *(float4*)(r1 + (long long)node * F_HID + 4 * fl) = o;
    }
}

// ---- GEMM2: h2b[100000,64] (bf16) = r1 @ W2f. BM=64, BN=64, BK=32, 256 thr ----
__global__ void g7_gemm2(const float* r1, const float* W2, unsigned short* h2b) {
    __shared__ float Rs[32][68];
    __shared__ float Ws[32][64];
    int tid = threadIdx.x;
    int m0 = blockIdx.x * 64;
    int tx = tid & 15;
    int ty = tid >> 4;
    float acc[4][4];
#pragma unroll
    for (int i = 0; i < 4; ++i) {
#pragma unroll
        for (int j = 0; j < 4; ++j) acc[i][j] = 0.0f;
    }

    for (int k0 = 0; k0 < F_HID; k0 += 32) {
#pragma unroll
        for (int r = 0; r < 8; ++r) {
            int i = r * 256 + tid;
            int kk = i & 31;
            int mm = i >> 5;
            int m = m0 + mm;
            float v = 0.0f;
            if (m < N_NODES) {
                v = r1[(long long)m * F_HID + k0 + kk];
            }
            Rs[kk][mm] = v;
        }
#pragma unroll
        for (int r = 0; r < 8; ++r) {
            int i = r * 256 + tid;
            int wk = i >> 6;
            int wn = i & 63;
            Ws[wk][wn] = W2[(k0 + wk) * F_OUT + wn];
        }
        __syncthreads();
#pragma unroll
        for (int k = 0; k < 32; ++k) {
            float a[4];
            float b[4];
#pragma unroll
            for (int i = 0; i < 4; ++i) a[i] = Rs[k][ty * 4 + i];
#pragma unroll
            for (int j = 0; j < 4; ++j) b[j] = Ws[k][tx * 4 + j];
#pragma unroll
            for (int i = 0; i < 4; ++i) {
#pragma unroll
                for (int j = 0; j < 4; ++j) acc[i][j] += a[i] * b[j];
            }
        }
        __syncthreads();
    }
#pragma unroll
    for (int i = 0; i < 4; ++i) {
        int m = m0 + ty * 4 + i;
        if (m < N_NODES) {
            unsigned int w0 = (unsigned int)g7_f2bf(acc[i][0])
                            | ((unsigned int)g7_f2bf(acc[i][1]) << 16);
            unsigned int w1 = (unsigned int)g7_f2bf(acc[i][2])
                            | ((unsigned int)g7_f2bf(acc[i][3]) << 16);
            uint2 o; o.x = w0; o.y = w1;
            *(uint2*)(h2b + (long long)m * F_OUT + tx * 4) = o;
        }
    }
}

// ---- agg2 CSR gather (bf16 table) + final epilogue, dual-edge halves.
// Lane fl owns features 2fl,2fl+1 (one u32). out in input float format. ----
__global__ void g7_agg2(const int* rowptr, const int* csr, const float* dinv,
                        const unsigned short* h2b, const float* b2, const int* fflag,
                        void* out) {
    int node = blockIdx.x * 4 + (threadIdx.x >> 6);
    int lane = threadIdx.x & 63;
    int e = lane >> 5;
    int fl = lane & 31;
    if (node >= N_NODES) return;
    int beg = rowptr[node];
    int end = rowptr[node + 1];
    const u32* hv = (const u32*)h2b;   // row = 32 u32
    float a0 = 0.f, a1 = 0.f;
    int j = beg + e;
    for (; j + 2 < end; j += 4) {
        int s0 = csr[j];
        int s1 = csr[j + 2];
        float w0 = dinv[s0];
        float w1 = dinv[s1];
        u32 v0 = hv[(long long)s0 * 32 + fl];
        u32 v1 = hv[(long long)s1 * 32 + fl];
        float2 p0 = g7_up(v0);
        float2 p1 = g7_up(v1);
        a0 += p0.x * w0 + p1.x * w1;
        a1 += p0.y * w0 + p1.y * w1;
    }
    if (j < end) {
        int s0 = csr[j];
        float w0 = dinv[s0];
        u32 v0 = hv[(long long)s0 * 32 + fl];
        float2 p0 = g7_up(v0);
        a0 += p0.x * w0;
        a1 += p0.y * w0;
    }
    float di = dinv[node];
    if (e == 0) {
        u32 vd = hv[(long long)node * 32 + fl];
        float2 pd = g7_up(vd);
        a0 += pd.x * di;
        a1 += pd.y * di;
    }
    a0 += __shfl_xor(a0, 32);
    a1 += __shfl_xor(a1, 32);
    if (e == 0) {
        float v0 = a0 * di + b2[2 * fl];
        float v1 = a1 * di + b2[2 * fl + 1];
        long long oi = (long long)node * F_OUT + 2 * fl;
        if (fflag[0] == 1) {
            u32 o = (u32)g7_f2bf(v0) | ((u32)g7_f2bf(v1) << 16);
            *(u32*)((unsigned short*)out + oi) = o;
        } else {
            float2 o; o.x = v0; o.y = v1;
            *(float2*)((float*)out + oi) = o;
        }
    }
}

extern "C" void kernel_launch(void* const* d_in, const int* in_sizes, int n_in,
                              void* d_out, int out_size, void* d_ws, size_t ws_size,
                              hipStream_t stream) {
    const void* x     = d_in[0];
    const int* ei_raw = (const int*)d_in[1];
    const void* W1    = d_in[2];
    const void* b1    = d_in[3];
    const void* W2    = d_in[4];
    const void* b2    = d_in[5];

    const int NBLK = (N_NODES + 255) / 256;   // 391

    // workspace layout (byte offsets, 16B-aligned):
    char* ws = (char*)d_ws;
    int*   deg    = (int*)(ws + 0);            //    400,000 B
    int*   iflag  = (int*)(ws + 409600);       //          4 B
    int*   fflag  = (int*)(ws + 409616);       //          4 B
    int*   bsum   = (int*)(ws + 409632);       //      1,564 B
    int*   boff   = (int*)(ws + 412800);       //      1,564 B
    float* dinv   = (float*)(ws + 524288);     //    400,000 B
    unsigned short* W1Th = (unsigned short*)(ws + 1048576); // 131,072 B
    unsigned short* W1Tl = (unsigned short*)(ws + 1179648); // 131,072 B
    float* b1f    = (float*)(ws + 1310720);    //        512 B
    float* W2f    = (float*)(ws + 1311232);    //     32,768 B
    float* b2f    = (float*)(ws + 1344000);    //        256 B
    int*   ei     = (int*)(ws + 2097152);      // 12,800,000 B
    int*   rowptr = (int*)(ws + 14897152);     //    400,004 B
    int*   cursor = (int*)(ws + 15298560);     //    400,000 B
    int*   csr    = (int*)(ws + 16777216);     //  6,400,000 B
    unsigned short* h1b = (unsigned short*)(ws + 23177216); // 25,600,000 B
    float* r1     = (float*)(ws + 74377216);   // 51,200,000 B
    unsigned short* h2b = (unsigned short*)(ws + 125577216); // 12,800,000 B

    g7_zero<<<(N_NODES + 255) / 256, 256, 0, stream>>>(deg, N_NODES);

    g7_iprobe<<<1, 64, 0, stream>>>(ei_raw, iflag);
    g7_fprobe<<<1, 64, 0, stream>>>((const unsigned int*)x, fflag);

    g7_pack<<<(2 * N_EDGES + 255) / 256, 256, 0, stream>>>(ei_raw, iflag, ei);

    g7_cvt<<<1, 128, 0, stream>>>(b1, fflag, b1f, F_HID);
    g7_cvt<<<(F_HID * F_OUT + 255) / 256, 256, 0, stream>>>(W2, fflag, W2f, F_HID * F_OUT);
    g7_cvt<<<1, 64, 0, stream>>>(b2, fflag, b2f, F_OUT);
    g7_w1s<<<(F_IN * F_HID + 255) / 256, 256, 0, stream>>>(W1, fflag, W1Th, W1Tl);

    g7_deg<<<(N_EDGES + 255) / 256, 256, 0, stream>>>(ei, deg);
    g7_dinv<<<(N_NODES + 255) / 256, 256, 0, stream>>>(deg, dinv);

    // CSR build
    g7_bsum<<<NBLK, 256, 0, stream>>>(deg, bsum);
    g7_bscan<<<1, 64, 0, stream>>>(bsum, boff, NBLK, rowptr);
    g7_scan<<<NBLK, 256, 0, stream>>>(deg, boff, rowptr, cursor);
    g7_scatter<<<(N_EDGES + 255) / 256, 256, 0, stream>>>(ei, cursor, csr);

    // GEMM1: split-bf16 MFMA (fp32-class accuracy), bf16 output table
    g7_gemm1s<<<(N_NODES + 127) / 128, 256, 0, stream>>>(x, fflag, W1Th, W1Tl, h1b);

    g7_agg1<<<N_NODES / 4, 256, 0, stream>>>(rowptr, csr, dinv, h1b, b1f, r1);

    g7_gemm2<<<(N_NODES + 63) / 64, 256, 0, stream>>>(r1, W2f, h2b);

    g7_agg2<<<N_NODES / 4, 256, 0, stream>>>(rowptr, csr, dinv, h2b, b2f, fflag, d_out);
}

// Round 4
// 784.790 us; speedup vs baseline: 1.6366x; 1.2350x over previous
//
#include <hip/hip_runtime.h>

#define N_NODES 100000
#define N_EDGES 1600000
#define F_IN 512
#define F_HID 128
#define F_OUT 64

typedef unsigned int u32;
typedef __attribute__((ext_vector_type(8))) short bf16x8;
typedef __attribute__((ext_vector_type(4))) float f32x4;

__device__ float g7_bf2f(unsigned short u) {
    return __uint_as_float(((unsigned int)u) << 16);
}

__device__ unsigned short g7_f2bf(float f) {
    unsigned int u = __float_as_uint(f);
    u = u + 0x7fffu + ((u >> 16) & 1u);
    return (unsigned short)(u >> 16);
}

// unpack a u32 of 2 packed bf16 -> (lo, hi) floats
__device__ float2 g7_up(unsigned int u) {
    float2 r;
    r.x = __uint_as_float(u << 16);
    r.y = __uint_as_float(u & 0xffff0000u);
    return r;
}

__device__ static inline void g7_gl2lds16(const void* g, void* l) {
    __builtin_amdgcn_global_load_lds(
        (const __attribute__((address_space(1))) u32*)g,
        (__attribute__((address_space(3))) u32*)l, 16, 0, 0);
}

__global__ void GCN_16716012716713_kernel() {}

__global__ void g7_zero(int* p, int n) {
    int i = blockIdx.x * blockDim.x + threadIdx.x;
    if (i < n) p[i] = 0;
}

// edge_index dtype probe: 1=int32, 0=int64 (int64 has all-zero high words).
// Parallel: 256 threads x 4 elems + LDS OR-reduce (was 1-thread serial, 40us).
__global__ void g7_iprobe(const int* raw, int* iflag) {
    __shared__ int s[256];
    int tid = threadIdx.x;
    int f = 0;
    for (int i = tid; i < 1024; i += 256) {
        if (raw[2 * i + 1] != 0) f = 1;
    }
    s[tid] = f;
    __syncthreads();
    for (int off = 128; off > 0; off >>= 1) {
        if (tid < off) s[tid] |= s[tid + off];
        __syncthreads();
    }
    if (tid == 0) iflag[0] = s[0];
}

// float dtype probe on x: 1=bf16, 0=fp32.
// Parallel: 256 threads x 16 elems + LDS sum-reduce (was 1-thread serial, 150us).
__global__ void g7_fprobe(const unsigned int* xw, int* fflag) {
    __shared__ int s[256];
    int tid = threadIdx.x;
    int cnt = 0;
    for (int i = tid; i < 4096; i += 256) {
        unsigned int lo = xw[i] & 0xffffu;
        unsigned int e = (lo >> 7) & 0xffu;
        if (e >= 110u && e <= 140u) cnt = cnt + 1;
    }
    s[tid] = cnt;
    __syncthreads();
    for (int off = 128; off > 0; off >>= 1) {
        if (tid < off) s[tid] += s[tid + off];
        __syncthreads();
    }
    if (tid == 0) fflag[0] = (s[0] > 2048) ? 1 : 0;
}

__global__ void g7_pack(const int* raw, const int* iflag, int* ei) {
    int i = blockIdx.x * blockDim.x + threadIdx.x;
    if (i < 2 * N_EDGES) {
        if (iflag[0] == 0) {
            ei[i] = raw[2 * i];
        } else {
            ei[i] = raw[i];
        }
    }
}

__global__ void g7_cvt(const void* src, const int* fflag, float* dst, int n) {
    int i = blockIdx.x * blockDim.x + threadIdx.x;
    if (i < n) {
        if (fflag[0] == 1) {
            dst[i] = g7_bf2f(((const unsigned short*)src)[i]);
        } else {
            dst[i] = ((const float*)src)[i];
        }
    }
}

// W1T split: W1Th[n][k] = bf16_hi(W1[k][n]), W1Tl[n][k] = bf16(W1 - hi).
__global__ void g7_w1s(const void* W1, const int* fflag,
                       unsigned short* W1Th, unsigned short* W1Tl) {
    int i = blockIdx.x * blockDim.x + threadIdx.x;
    if (i < F_IN * F_HID) {
        int k = i >> 7;
        int n = i & 127;
        float w;
        if (fflag[0] == 1) {
            w = g7_bf2f(((const unsigned short*)W1)[i]);
        } else {
            w = ((const float*)W1)[i];
        }
        unsigned short hi = g7_f2bf(w);
        unsigned short lo = g7_f2bf(w - g7_bf2f(hi));
        W1Th[n * F_IN + k] = hi;
        W1Tl[n * F_IN + k] = lo;
    }
}

__global__ void g7_deg(const int* ei, int* deg) {
    int e = blockIdx.x * blockDim.x + threadIdx.x;
    if (e < N_EDGES) {
        atomicAdd(&deg[ei[N_EDGES + e]], 1);
    }
}

__global__ void g7_dinv(const int* deg, float* dinv) {
    int i = blockIdx.x * blockDim.x + threadIdx.x;
    if (i < N_NODES) {
        dinv[i] = rsqrtf((float)deg[i] + 1.0f);
    }
}

// ---- CSR build: block-sums -> serial scan of 391 block sums -> per-block scan ----
__global__ void g7_bsum(const int* deg, int* bsum) {
    __shared__ int s[256];
    int i = blockIdx.x * 256 + threadIdx.x;
    s[threadIdx.x] = (i < N_NODES) ? deg[i] : 0;
    __syncthreads();
    for (int off = 128; off > 0; off >>= 1) {
        if (threadIdx.x < off) s[threadIdx.x] += s[threadIdx.x + off];
        __syncthreads();
    }
    if (threadIdx.x == 0) bsum[blockIdx.x] = s[0];
}

__global__ void g7_bscan(const int* bsum, int* boff, int nblk, int* rowptr) {
    if (blockIdx.x == 0 && threadIdx.x == 0) {
        int acc = 0;
        for (int b = 0; b < nblk; b = b + 1) {
            boff[b] = acc;
            acc = acc + bsum[b];
        }
        rowptr[N_NODES] = acc;   // == N_EDGES
    }
}

__global__ void g7_scan(const int* deg, const int* boff, int* rowptr, int* cursor) {
    __shared__ int s[256];
    int i = blockIdx.x * 256 + threadIdx.x;
    int v = (i < N_NODES) ? deg[i] : 0;
    s[threadIdx.x] = v;
    __syncthreads();
    for (int off = 1; off < 256; off <<= 1) {
        int t = (threadIdx.x >= off) ? s[threadIdx.x - off] : 0;
        __syncthreads();
        s[threadIdx.x] += t;
        __syncthreads();
    }
    if (i < N_NODES) {
        int excl = s[threadIdx.x] - v + boff[blockIdx.x];
        rowptr[i] = excl;
        cursor[i] = excl;
    }
}

// scatter src ids into dst-grouped CSR order
__global__ void g7_scatter(const int* ei, int* cursor, int* csr) {
    int e = blockIdx.x * blockDim.x + threadIdx.x;
    if (e < N_EDGES) {
        int s = ei[e];
        int d = ei[N_EDGES + e];
        int pos = atomicAdd(&cursor[d], 1);
        csr[pos] = s;
    }
}

// ---- GEMM1 split-bf16 MFMA: h1[100000,128] = x @ W1, fp32-class accuracy.
// Output stored as bf16 (h1b) to halve agg1 gather traffic. ----
__global__ __launch_bounds__(256, 2) void g7_gemm1s(const void* x, const int* fflag,
        const unsigned short* W1Th, const unsigned short* W1Tl, unsigned short* h1b) {
    __shared__ uint4 smv[4096];          // 64 KB: 2 x (A 16K + B 16K)
    char* smc = (char*)smv;
    int tid = threadIdx.x;
    int m0 = blockIdx.x * 128;
    int w = tid >> 6;
    int lane = tid & 63;
    int wr = w >> 1, wc = w & 1;         // wave grid 2x2
    int la = lane & 15;                  // mfma row/col within 16
    int lk = lane >> 4;                  // mfma k-group (8 bf16 = 16 B)
    int isbf = fflag[0];
    int ar = tid >> 1;                   // A staging: row
    int ah = tid & 1;                    // A staging: k-half (16 elems)

    f32x4 acc[4][4];
#pragma unroll
    for (int i = 0; i < 4; ++i)
#pragma unroll
        for (int j = 0; j < 4; ++j) acc[i][j] = (f32x4){0.f, 0.f, 0.f, 0.f};

    uint4 rA[4];

    // issue A-tile global loads (16 fp32 or 16 bf16 per thread), no wait
    auto loadA = [&](int k0) {
        int m = m0 + ar;
        if (m >= N_NODES) m = N_NODES - 1;   // dup-read, discarded at store
        if (isbf) {
            const char* s = (const char*)x + ((long long)m * F_IN + k0 + ah * 16) * 2;
            rA[0] = *(const uint4*)s;
            rA[1] = *(const uint4*)(s + 16);
        } else {
            const char* s = (const char*)x + ((long long)m * F_IN + k0 + ah * 16) * 4;
            rA[0] = *(const uint4*)s;
            rA[1] = *(const uint4*)(s + 16);
            rA[2] = *(const uint4*)(s + 32);
            rA[3] = *(const uint4*)(s + 48);
        }
    };

    // convert regs -> hi/lo bf16, swizzled ds_write (called AFTER compute)
    auto writeA = [&](char* As) {
        float f[16];
        if (isbf) {
            const unsigned short* p = (const unsigned short*)rA;
#pragma unroll
            for (int j = 0; j < 16; ++j) f[j] = g7_bf2f(p[j]);
        } else {
            const float* p = (const float*)rA;
#pragma unroll
            for (int j = 0; j < 16; ++j) f[j] = p[j];
        }
        unsigned int hw[8], lw[8];
#pragma unroll
        for (int j = 0; j < 8; ++j) {
            unsigned short h0 = g7_f2bf(f[2 * j]);
            unsigned short h1v = g7_f2bf(f[2 * j + 1]);
            unsigned short l0 = g7_f2bf(f[2 * j] - g7_bf2f(h0));
            unsigned short l1 = g7_f2bf(f[2 * j + 1] - g7_bf2f(h1v));
            hw[j] = (unsigned int)h0 | ((unsigned int)h1v << 16);
            lw[j] = (unsigned int)l0 | ((unsigned int)l1 << 16);
        }
        int swz = (ar & 7) << 4;
        char* dst = As + ar * 128;
        *(uint4*)(dst + ((ah * 32 + 0) ^ swz))      = make_uint4(hw[0], hw[1], hw[2], hw[3]);
        *(uint4*)(dst + ((ah * 32 + 16) ^ swz))     = make_uint4(hw[4], hw[5], hw[6], hw[7]);
        *(uint4*)(dst + ((64 + ah * 32 + 0) ^ swz)) = make_uint4(lw[0], lw[1], lw[2], lw[3]);
        *(uint4*)(dst + ((64 + ah * 32 + 16) ^ swz))= make_uint4(lw[4], lw[5], lw[6], lw[7]);
    };

    // B-tile: rows n 0..127, 128B = [hi|lo], linear LDS dest + inverse-swizzled source
    auto stageB = [&](char* Bs, int k0) {
#pragma unroll
        for (int p = 0; p < 4; ++p) {
            int nr = w * 32 + p * 8 + (lane >> 3);
            int cp = ((lane & 7) * 16) ^ (((lane >> 3) & 7) << 4);  // source col in [0,128)
            const char* src = (cp < 64)
                ? (const char*)W1Th + (long long)nr * 1024 + k0 * 2 + cp
                : (const char*)W1Tl + (long long)nr * 1024 + k0 * 2 + (cp - 64);
            g7_gl2lds16(src, Bs + (w * 32 + p * 8) * 128);
        }
    };

    auto compute = [&](const char* As, const char* Bs) {
        bf16x8 a_hi[4], a_lo[4], b_hi[4], b_lo[4];
#pragma unroll
        for (int i = 0; i < 4; ++i) {
            int r = wr * 64 + i * 16 + la;
            int swz = (r & 7) << 4;
            const char* ab = As + r * 128;
            a_hi[i] = *(const bf16x8*)(ab + ((lk * 16) ^ swz));
            a_lo[i] = *(const bf16x8*)(ab + ((64 + lk * 16) ^ swz));
            int n = wc * 64 + i * 16 + la;
            int swzb = (n & 7) << 4;
            const char* bb = Bs + n * 128;
            b_hi[i] = *(const bf16x8*)(bb + ((lk * 16) ^ swzb));
            b_lo[i] = *(const bf16x8*)(bb + ((64 + lk * 16) ^ swzb));
        }
#pragma unroll
        for (int i = 0; i < 4; ++i)
#pragma unroll
            for (int j = 0; j < 4; ++j) {
                acc[i][j] = __builtin_amdgcn_mfma_f32_16x16x32_bf16(
                    a_hi[i], b_hi[j], acc[i][j], 0, 0, 0);
                acc[i][j] = __builtin_amdgcn_mfma_f32_16x16x32_bf16(
                    a_lo[i], b_hi[j], acc[i][j], 0, 0, 0);
                acc[i][j] = __builtin_amdgcn_mfma_f32_16x16x32_bf16(
                    a_hi[i], b_lo[j], acc[i][j], 0, 0, 0);
            }
    };

    // prologue: stage K-step 0 into buffer 0
    loadA(0);
    stageB(smc + 16384, 0);
    writeA(smc);
    __syncthreads();                      // drains vmcnt: buf0 ready

    for (int kt = 0; kt < 16; ++kt) {
        char* bc = smc + (kt & 1) * 32768;
        char* bn = smc + ((kt & 1) ^ 1) * 32768;
        if (kt < 15) {                    // issue next-tile loads early (T14)
            loadA((kt + 1) * 32);
            stageB(bn + 16384, (kt + 1) * 32);
        }
        compute(bc, bc + 16384);
        if (kt < 15) writeA(bn);          // convert-late: vmcnt wait lands here
        __syncthreads();
    }

    // epilogue: D row = lk*4+q (m), col = la (n) per 16x16 fragment; bf16 store
#pragma unroll
    for (int i = 0; i < 4; ++i) {
#pragma unroll
        for (int j = 0; j < 4; ++j) {
            int n = wc * 64 + j * 16 + la;
#pragma unroll
            for (int q = 0; q < 4; ++q) {
                int m = m0 + wr * 64 + i * 16 + lk * 4 + q;
                if (m < N_NODES) {
                    h1b[(long long)m * F_HID + n] = g7_f2bf(acc[i][j][q]);
                }
            }
        }
    }
}

// ---- agg1 CSR gather, bf16 table, dual-edge halves + 2-wide unroll (4 gathers in flight).
// Wave = 1 node. Halves (lanes 0-31 / 32-63) own alternating edges; lane fl owns
// features 4fl..4fl+3 (uint2 of 4 packed bf16). Self-loop folded as edge w=dinv[d].
// r1[d] = relu(dinv[d]*acc + b1), fp32. ----
__global__ void g7_agg1(const int* rowptr, const int* csr, const float* dinv,
                        const unsigned short* h1b, const float* b1, float* r1) {
    int node = blockIdx.x * 4 + (threadIdx.x >> 6);
    int lane = threadIdx.x & 63;
    int e = lane >> 5;
    int fl = lane & 31;
    if (node >= N_NODES) return;
    int beg = rowptr[node];
    int end = rowptr[node + 1];
    const uint2* hv = (const uint2*)h1b;   // row = 32 uint2
    float a0 = 0.f, a1 = 0.f, a2 = 0.f, a3 = 0.f;
    int j = beg + e;
    for (; j + 2 < end; j += 4) {
        int s0 = csr[j];
        int s1 = csr[j + 2];
        float w0 = dinv[s0];
        float w1 = dinv[s1];
        uint2 v0 = hv[(long long)s0 * 32 + fl];
        uint2 v1 = hv[(long long)s1 * 32 + fl];
        float2 p0 = g7_up(v0.x), q0 = g7_up(v0.y);
        float2 p1 = g7_up(v1.x), q1 = g7_up(v1.y);
        a0 += p0.x * w0 + p1.x * w1;
        a1 += p0.y * w0 + p1.y * w1;
        a2 += q0.x * w0 + q1.x * w1;
        a3 += q0.y * w0 + q1.y * w1;
    }
    if (j < end) {
        int s0 = csr[j];
        float w0 = dinv[s0];
        uint2 v0 = hv[(long long)s0 * 32 + fl];
        float2 p0 = g7_up(v0.x), q0 = g7_up(v0.y);
        a0 += p0.x * w0;
        a1 += p0.y * w0;
        a2 += q0.x * w0;
        a3 += q0.y * w0;
    }
    float di = dinv[node];
    if (e == 0) {                     // self-loop as an edge with w = dinv[node]
        uint2 vd = hv[(long long)node * 32 + fl];
        float2 pd = g7_up(vd.x), qd = g7_up(vd.y);
        a0 += pd.x * di;
        a1 += pd.y * di;
        a2 += qd.x * di;
        a3 += qd.y * di;
    }
    a0 += __shfl_xor(a0, 32);
    a1 += __shfl_xor(a1, 32);
    a2 += __shfl_xor(a2, 32);
    a3 += __shfl_xor(a3, 32);
    if (e == 0) {
        float4 bb = *(const float4*)(b1 + 4 * fl);
        float r0 = a0 * di + bb.x;
        float r1v = a1 * di + bb.y;
        float r2 = a2 * di + bb.z;
        float r3 = a3 * di + bb.w;
        if (r0 < 0.f) r0 = 0.f;
        if (r1v < 0.f) r1v = 0.f;
        if (r2 < 0.f) r2 = 0.f;
        if (r3 < 0.f) r3 = 0.f;
        float4 o;
        o.x = r0; o.y = r1v; o.z = r2; o.w = r3;
        *(float4*)(r1 + (long long)node * F_HID + 4 * fl) = o;
    }
}

// ---- GEMM2: h2b[100000,64] (bf16) = r1 @ W2f. BM=64, BN=64, BK=32, 256 thr ----
__global__ void g7_gemm2(const float* r1, const float* W2, unsigned short* h2b) {
    __shared__ float Rs[32][68];
    __shared__ float Ws[32][64];
    int tid = threadIdx.x;
    int m0 = blockIdx.x * 64;
    int tx = tid & 15;
    int ty = tid >> 4;
    float acc[4][4];
#pragma unroll
    for (int i = 0; i < 4; ++i) {
#pragma unroll
        for (int j = 0; j < 4; ++j) acc[i][j] = 0.0f;
    }

    for (int k0 = 0; k0 < F_HID; k0 += 32) {
#pragma unroll
        for (int r = 0; r < 8; ++r) {
            int i = r * 256 + tid;
            int kk = i & 31;
            int mm = i >> 5;
            int m = m0 + mm;
            float v = 0.0f;
            if (m < N_NODES) {
                v = r1[(long long)m * F_HID + k0 + kk];
            }
            Rs[kk][mm] = v;
        }
#pragma unroll
        for (int r = 0; r < 8; ++r) {
            int i = r * 256 + tid;
            int wk = i >> 6;
            int wn = i & 63;
            Ws[wk][wn] = W2[(k0 + wk) * F_OUT + wn];
        }
        __syncthreads();
#pragma unroll
        for (int k = 0; k < 32; ++k) {
            float a[4];
            float b[4];
#pragma unroll
            for (int i = 0; i < 4; ++i) a[i] = Rs[k][ty * 4 + i];
#pragma unroll
            for (int j = 0; j < 4; ++j) b[j] = Ws[k][tx * 4 + j];
#pragma unroll
            for (int i = 0; i < 4; ++i) {
#pragma unroll
                for (int j = 0; j < 4; ++j) acc[i][j] += a[i] * b[j];
            }
        }
        __syncthreads();
    }
#pragma unroll
    for (int i = 0; i < 4; ++i) {
        int m = m0 + ty * 4 + i;
        if (m < N_NODES) {
            unsigned int w0 = (unsigned int)g7_f2bf(acc[i][0])
                            | ((unsigned int)g7_f2bf(acc[i][1]) << 16);
            unsigned int w1 = (unsigned int)g7_f2bf(acc[i][2])
                            | ((unsigned int)g7_f2bf(acc[i][3]) << 16);
            uint2 o; o.x = w0; o.y = w1;
            *(uint2*)(h2b + (long long)m * F_OUT + tx * 4) = o;
        }
    }
}

// ---- agg2 CSR gather (bf16 table) + final epilogue, dual-edge halves.
// Lane fl owns features 2fl,2fl+1 (one u32). out in input float format. ----
__global__ void g7_agg2(const int* rowptr, const int* csr, const float* dinv,
                        const unsigned short* h2b, const float* b2, const int* fflag,
                        void* out) {
    int node = blockIdx.x * 4 + (threadIdx.x >> 6);
    int lane = threadIdx.x & 63;
    int e = lane >> 5;
    int fl = lane & 31;
    if (node >= N_NODES) return;
    int beg = rowptr[node];
    int end = rowptr[node + 1];
    const u32* hv = (const u32*)h2b;   // row = 32 u32
    float a0 = 0.f, a1 = 0.f;
    int j = beg + e;
    for (; j + 2 < end; j += 4) {
        int s0 = csr[j];
        int s1 = csr[j + 2];
        float w0 = dinv[s0];
        float w1 = dinv[s1];
        u32 v0 = hv[(long long)s0 * 32 + fl];
        u32 v1 = hv[(long long)s1 * 32 + fl];
        float2 p0 = g7_up(v0);
        float2 p1 = g7_up(v1);
        a0 += p0.x * w0 + p1.x * w1;
        a1 += p0.y * w0 + p1.y * w1;
    }
    if (j < end) {
        int s0 = csr[j];
        float w0 = dinv[s0];
        u32 v0 = hv[(long long)s0 * 32 + fl];
        float2 p0 = g7_up(v0);
        a0 += p0.x * w0;
        a1 += p0.y * w0;
    }
    float di = dinv[node];
    if (e == 0) {
        u32 vd = hv[(long long)node * 32 + fl];
        float2 pd = g7_up(vd);
        a0 += pd.x * di;
        a1 += pd.y * di;
    }
    a0 += __shfl_xor(a0, 32);
    a1 += __shfl_xor(a1, 32);
    if (e == 0) {
        float v0 = a0 * di + b2[2 * fl];
        float v1 = a1 * di + b2[2 * fl + 1];
        long long oi = (long long)node * F_OUT + 2 * fl;
        if (fflag[0] == 1) {
            u32 o = (u32)g7_f2bf(v0) | ((u32)g7_f2bf(v1) << 16);
            *(u32*)((unsigned short*)out + oi) = o;
        } else {
            float2 o; o.x = v0; o.y = v1;
            *(float2*)((float*)out + oi) = o;
        }
    }
}

extern "C" void kernel_launch(void* const* d_in, const int* in_sizes, int n_in,
                              void* d_out, int out_size, void* d_ws, size_t ws_size,
                              hipStream_t stream) {
    const void* x     = d_in[0];
    const int* ei_raw = (const int*)d_in[1];
    const void* W1    = d_in[2];
    const void* b1    = d_in[3];
    const void* W2    = d_in[4];
    const void* b2    = d_in[5];

    const int NBLK = (N_NODES + 255) / 256;   // 391

    // workspace layout (byte offsets, 16B-aligned):
    char* ws = (char*)d_ws;
    int*   deg    = (int*)(ws + 0);            //    400,000 B
    int*   iflag  = (int*)(ws + 409600);       //          4 B
    int*   fflag  = (int*)(ws + 409616);       //          4 B
    int*   bsum   = (int*)(ws + 409632);       //      1,564 B
    int*   boff   = (int*)(ws + 412800);       //      1,564 B
    float* dinv   = (float*)(ws + 524288);     //    400,000 B
    unsigned short* W1Th = (unsigned short*)(ws + 1048576); // 131,072 B
    unsigned short* W1Tl = (unsigned short*)(ws + 1179648); // 131,072 B
    float* b1f    = (float*)(ws + 1310720);    //        512 B
    float* W2f    = (float*)(ws + 1311232);    //     32,768 B
    float* b2f    = (float*)(ws + 1344000);    //        256 B
    int*   ei     = (int*)(ws + 2097152);      // 12,800,000 B
    int*   rowptr = (int*)(ws + 14897152);     //    400,004 B
    int*   cursor = (int*)(ws + 15298560);     //    400,000 B
    int*   csr    = (int*)(ws + 16777216);     //  6,400,000 B
    unsigned short* h1b = (unsigned short*)(ws + 23177216); // 25,600,000 B
    float* r1     = (float*)(ws + 74377216);   // 51,200,000 B
    unsigned short* h2b = (unsigned short*)(ws + 125577216); // 12,800,000 B

    g7_zero<<<(N_NODES + 255) / 256, 256, 0, stream>>>(deg, N_NODES);

    g7_iprobe<<<1, 256, 0, stream>>>(ei_raw, iflag);
    g7_fprobe<<<1, 256, 0, stream>>>((const unsigned int*)x, fflag);

    g7_pack<<<(2 * N_EDGES + 255) / 256, 256, 0, stream>>>(ei_raw, iflag, ei);

    g7_cvt<<<1, 128, 0, stream>>>(b1, fflag, b1f, F_HID);
    g7_cvt<<<(F_HID * F_OUT + 255) / 256, 256, 0, stream>>>(W2, fflag, W2f, F_HID * F_OUT);
    g7_cvt<<<1, 64, 0, stream>>>(b2, fflag, b2f, F_OUT);
    g7_w1s<<<(F_IN * F_HID + 255) / 256, 256, 0, stream>>>(W1, fflag, W1Th, W1Tl);

    g7_deg<<<(N_EDGES + 255) / 256, 256, 0, stream>>>(ei, deg);
    g7_dinv<<<(N_NODES + 255) / 256, 256, 0, stream>>>(deg, dinv);

    // CSR build
    g7_bsum<<<NBLK, 256, 0, stream>>>(deg, bsum);
    g7_bscan<<<1, 64, 0, stream>>>(bsum, boff, NBLK, rowptr);
    g7_scan<<<NBLK, 256, 0, stream>>>(deg, boff, rowptr, cursor);
    g7_scatter<<<(N_EDGES + 255) / 256, 256, 0, stream>>>(ei, cursor, csr);

    // GEMM1: split-bf16 MFMA (fp32-class accuracy), bf16 output table
    g7_gemm1s<<<(N_NODES + 127) / 128, 256, 0, stream>>>(x, fflag, W1Th, W1Tl, h1b);

    g7_agg1<<<N_NODES / 4, 256, 0, stream>>>(rowptr, csr, dinv, h1b, b1f, r1);

    g7_gemm2<<<(N_NODES + 63) / 64, 256, 0, stream>>>(r1, W2f, h2b);

    g7_agg2<<<N_NODES / 4, 256, 0, stream>>>(rowptr, csr, dinv, h2b, b2f, fflag, d_out);
}

// Round 5
// 648.507 us; speedup vs baseline: 1.9805x; 1.2101x over previous
//
#include <hip/hip_runtime.h>

#define N_NODES 100000
#define N_EDGES 1600000
#define F_IN 512
#define F_HID 128
#define F_OUT 64

#define BSH 8                      // bucket = dst >> 8 (256 nodes / bucket)
#define NBUK 391                   // ceil(100000/256)

typedef unsigned int u32;
typedef __attribute__((ext_vector_type(8))) short bf16x8;
typedef __attribute__((ext_vector_type(4))) float f32x4;

__device__ float g7_bf2f(unsigned short u) {
    return __uint_as_float(((unsigned int)u) << 16);
}

__device__ unsigned short g7_f2bf(float f) {
    unsigned int u = __float_as_uint(f);
    u = u + 0x7fffu + ((u >> 16) & 1u);
    return (unsigned short)(u >> 16);
}

// unpack a u32 of 2 packed bf16 -> (lo, hi) floats
__device__ float2 g7_up(unsigned int u) {
    float2 r;
    r.x = __uint_as_float(u << 16);
    r.y = __uint_as_float(u & 0xffff0000u);
    return r;
}

__device__ static inline void g7_gl2lds16(const void* g, void* l) {
    __builtin_amdgcn_global_load_lds(
        (const __attribute__((address_space(1))) u32*)g,
        (__attribute__((address_space(3))) u32*)l, 16, 0, 0);
}

__global__ void GCN_16716012716713_kernel() {}

__global__ void g7_zero(int* p, int n) {
    int i = blockIdx.x * blockDim.x + threadIdx.x;
    if (i < n) p[i] = 0;
}

// edge_index dtype probe: 1=int32, 0=int64 (int64 has all-zero high words).
__global__ void g7_iprobe(const int* raw, int* iflag) {
    __shared__ int s[256];
    int tid = threadIdx.x;
    int f = 0;
    for (int i = tid; i < 1024; i += 256) {
        if (raw[2 * i + 1] != 0) f = 1;
    }
    s[tid] = f;
    __syncthreads();
    for (int off = 128; off > 0; off >>= 1) {
        if (tid < off) s[tid] |= s[tid + off];
        __syncthreads();
    }
    if (tid == 0) iflag[0] = s[0];
}

// float dtype probe on x: 1=bf16, 0=fp32.
__global__ void g7_fprobe(const unsigned int* xw, int* fflag) {
    __shared__ int s[256];
    int tid = threadIdx.x;
    int cnt = 0;
    for (int i = tid; i < 4096; i += 256) {
        unsigned int lo = xw[i] & 0xffffu;
        unsigned int e = (lo >> 7) & 0xffu;
        if (e >= 110u && e <= 140u) cnt = cnt + 1;
    }
    s[tid] = cnt;
    __syncthreads();
    for (int off = 128; off > 0; off >>= 1) {
        if (tid < off) s[tid] += s[tid + off];
        __syncthreads();
    }
    if (tid == 0) fflag[0] = (s[0] > 2048) ? 1 : 0;
}

// pack edge ids to int32 + fused in-degree count (dst half)
__global__ void g7_pack(const int* raw, const int* iflag, int* ei, int* deg) {
    int i = blockIdx.x * blockDim.x + threadIdx.x;
    if (i < 2 * N_EDGES) {
        int v;
        if (iflag[0] == 0) {
            v = raw[2 * i];
        } else {
            v = raw[i];
        }
        ei[i] = v;
        if (i >= N_EDGES) atomicAdd(&deg[v], 1);
    }
}

__global__ void g7_cvt(const void* src, const int* fflag, float* dst, int n) {
    int i = blockIdx.x * blockDim.x + threadIdx.x;
    if (i < n) {
        if (fflag[0] == 1) {
            dst[i] = g7_bf2f(((const unsigned short*)src)[i]);
        } else {
            dst[i] = ((const float*)src)[i];
        }
    }
}

// W1T split: W1Th[n][k] = bf16_hi(W1[k][n]), W1Tl[n][k] = bf16(W1 - hi).
__global__ void g7_w1s(const void* W1, const int* fflag,
                       unsigned short* W1Th, unsigned short* W1Tl) {
    int i = blockIdx.x * blockDim.x + threadIdx.x;
    if (i < F_IN * F_HID) {
        int k = i >> 7;
        int n = i & 127;
        float w;
        if (fflag[0] == 1) {
            w = g7_bf2f(((const unsigned short*)W1)[i]);
        } else {
            w = ((const float*)W1)[i];
        }
        unsigned short hi = g7_f2bf(w);
        unsigned short lo = g7_f2bf(w - g7_bf2f(hi));
        W1Th[n * F_IN + k] = hi;
        W1Tl[n * F_IN + k] = lo;
    }
}

__global__ void g7_dinv(const int* deg, float* dinv) {
    int i = blockIdx.x * blockDim.x + threadIdx.x;
    if (i < N_NODES) {
        dinv[i] = rsqrtf((float)deg[i] + 1.0f);
    }
}

// ---- CSR rowptr build: block-sums -> parallel scan of 391 block sums -> per-block scan ----
__global__ void g7_bsum(const int* deg, int* bsum) {
    __shared__ int s[256];
    int i = blockIdx.x * 256 + threadIdx.x;
    s[threadIdx.x] = (i < N_NODES) ? deg[i] : 0;
    __syncthreads();
    for (int off = 128; off > 0; off >>= 1) {
        if (threadIdx.x < off) s[threadIdx.x] += s[threadIdx.x + off];
        __syncthreads();
    }
    if (threadIdx.x == 0) bsum[blockIdx.x] = s[0];
}

// parallel Hillis-Steele scan of nblk (<=512) block sums, 1 block x 512 thr
__global__ void g7_bscan(const int* bsum, int* boff, int nblk, int* rowptr) {
    __shared__ int s[512];
    int tid = threadIdx.x;
    int v = (tid < nblk) ? bsum[tid] : 0;
    s[tid] = v;
    __syncthreads();
    for (int off = 1; off < 512; off <<= 1) {
        int t = (tid >= off) ? s[tid - off] : 0;
        __syncthreads();
        s[tid] += t;
        __syncthreads();
    }
    if (tid < nblk) boff[tid] = s[tid] - v;   // exclusive
    if (tid == nblk - 1) rowptr[N_NODES] = s[tid];
}

__global__ void g7_scan(const int* deg, const int* boff, int* rowptr) {
    __shared__ int s[256];
    int i = blockIdx.x * 256 + threadIdx.x;
    int v = (i < N_NODES) ? deg[i] : 0;
    s[threadIdx.x] = v;
    __syncthreads();
    for (int off = 1; off < 256; off <<= 1) {
        int t = (threadIdx.x >= off) ? s[threadIdx.x - off] : 0;
        __syncthreads();
        s[threadIdx.x] += t;
        __syncthreads();
    }
    if (i < N_NODES) {
        rowptr[i] = s[threadIdx.x] - v + boff[blockIdx.x];
    }
}

// init per-bucket cursors from rowptr (bucket b starts at node b*256)
__global__ void g7_binit(const int* rowptr, int* bcur) {
    int b = blockIdx.x * blockDim.x + threadIdx.x;
    if (b < NBUK) bcur[b] = rowptr[b << BSH];
}

// ---- partition pass 1: edges -> bucket-contiguous (src,dst) pairs.
// Per block: LDS count -> chunk reservation (1 global atomic per bucket) ->
// contiguous chunk writes. Kills the 16x write amplification of direct scatter. ----
#define P1_EPT 32
#define P1_TILE (256 * P1_EPT)   // 8192 edges/block, grid 196
__global__ void g7_part1(const int* ei, int* bcur, uint2* part) {
    __shared__ int cnt[NBUK + 1];
    __shared__ int base[NBUK + 1];
    int tid = threadIdx.x;
    long long t0 = (long long)blockIdx.x * P1_TILE;
    for (int i = tid; i < NBUK; i += 256) cnt[i] = 0;
    __syncthreads();
#pragma unroll 4
    for (int r = 0; r < P1_EPT; ++r) {
        long long e = t0 + r * 256 + tid;
        if (e < N_EDGES) {
            int d = ei[N_EDGES + e];
            atomicAdd(&cnt[d >> BSH], 1);
        }
    }
    __syncthreads();
    for (int i = tid; i < NBUK; i += 256) {
        int c = cnt[i];
        base[i] = (c > 0) ? atomicAdd(&bcur[i], c) : 0;
        cnt[i] = 0;                 // reuse as local cursor
    }
    __syncthreads();
#pragma unroll 4
    for (int r = 0; r < P1_EPT; ++r) {
        long long e = t0 + r * 256 + tid;
        if (e < N_EDGES) {
            int s = ei[e];
            int d = ei[N_EDGES + e];
            int bk = d >> BSH;
            int off = atomicAdd(&cnt[bk], 1);
            uint2 p; p.x = (u32)s; p.y = (u32)d;
            part[(long long)base[bk] + off] = p;
        }
    }
}

// ---- partition pass 2: within-bucket exact scatter via LDS cursors.
// One block per bucket; csr window ~16KB, cursor atomics in LDS. ----
__global__ void g7_part2(const int* rowptr, const uint2* part, int* csr) {
    __shared__ int lcur[256];
    int b = blockIdx.x;
    int tid = threadIdx.x;
    int n0 = b << BSH;
    int n1 = n0 + 256; if (n1 > N_NODES) n1 = N_NODES;
    if (tid < 256) {
        int node = n0 + tid;
        lcur[tid] = (node < N_NODES) ? rowptr[node] : 0;
    }
    __syncthreads();
    int beg = rowptr[n0];
    int end = rowptr[n1];
    for (int j = beg + tid; j < end; j += 512) {
        uint2 p = part[j];
        int pos = atomicAdd(&lcur[p.y - n0], 1);
        csr[pos] = (int)p.x;
    }
}

// ---- GEMM1 split-bf16 MFMA: h1[100000,128] = x @ W1, fp32-class accuracy.
// Output stored as bf16 (h1b) to halve agg1 gather traffic. ----
__global__ __launch_bounds__(256, 2) void g7_gemm1s(const void* x, const int* fflag,
        const unsigned short* W1Th, const unsigned short* W1Tl, unsigned short* h1b) {
    __shared__ uint4 smv[4096];          // 64 KB: 2 x (A 16K + B 16K)
    char* smc = (char*)smv;
    int tid = threadIdx.x;
    int m0 = blockIdx.x * 128;
    int w = tid >> 6;
    int lane = tid & 63;
    int wr = w >> 1, wc = w & 1;         // wave grid 2x2
    int la = lane & 15;                  // mfma row/col within 16
    int lk = lane >> 4;                  // mfma k-group (8 bf16 = 16 B)
    int isbf = fflag[0];
    int ar = tid >> 1;                   // A staging: row
    int ah = tid & 1;                    // A staging: k-half (16 elems)

    f32x4 acc[4][4];
#pragma unroll
    for (int i = 0; i < 4; ++i)
#pragma unroll
        for (int j = 0; j < 4; ++j) acc[i][j] = (f32x4){0.f, 0.f, 0.f, 0.f};

    uint4 rA[4];

    // issue A-tile global loads (16 fp32 or 16 bf16 per thread), no wait
    auto loadA = [&](int k0) {
        int m = m0 + ar;
        if (m >= N_NODES) m = N_NODES - 1;   // dup-read, discarded at store
        if (isbf) {
            const char* s = (const char*)x + ((long long)m * F_IN + k0 + ah * 16) * 2;
            rA[0] = *(const uint4*)s;
            rA[1] = *(const uint4*)(s + 16);
        } else {
            const char* s = (const char*)x + ((long long)m * F_IN + k0 + ah * 16) * 4;
            rA[0] = *(const uint4*)s;
            rA[1] = *(const uint4*)(s + 16);
            rA[2] = *(const uint4*)(s + 32);
            rA[3] = *(const uint4*)(s + 48);
        }
    };

    // convert regs -> hi/lo bf16, swizzled ds_write (called AFTER compute)
    auto writeA = [&](char* As) {
        float f[16];
        if (isbf) {
            const unsigned short* p = (const unsigned short*)rA;
#pragma unroll
            for (int j = 0; j < 16; ++j) f[j] = g7_bf2f(p[j]);
        } else {
            const float* p = (const float*)rA;
#pragma unroll
            for (int j = 0; j < 16; ++j) f[j] = p[j];
        }
        unsigned int hw[8], lw[8];
#pragma unroll
        for (int j = 0; j < 8; ++j) {
            unsigned short h0 = g7_f2bf(f[2 * j]);
            unsigned short h1v = g7_f2bf(f[2 * j + 1]);
            unsigned short l0 = g7_f2bf(f[2 * j] - g7_bf2f(h0));
            unsigned short l1 = g7_f2bf(f[2 * j + 1] - g7_bf2f(h1v));
            hw[j] = (unsigned int)h0 | ((unsigned int)h1v << 16);
            lw[j] = (unsigned int)l0 | ((unsigned int)l1 << 16);
        }
        int swz = (ar & 7) << 4;
        char* dst = As + ar * 128;
        *(uint4*)(dst + ((ah * 32 + 0) ^ swz))      = make_uint4(hw[0], hw[1], hw[2], hw[3]);
        *(uint4*)(dst + ((ah * 32 + 16) ^ swz))     = make_uint4(hw[4], hw[5], hw[6], hw[7]);
        *(uint4*)(dst + ((64 + ah * 32 + 0) ^ swz)) = make_uint4(lw[0], lw[1], lw[2], lw[3]);
        *(uint4*)(dst + ((64 + ah * 32 + 16) ^ swz))= make_uint4(lw[4], lw[5], lw[6], lw[7]);
    };

    // B-tile: rows n 0..127, 128B = [hi|lo], linear LDS dest + inverse-swizzled source
    auto stageB = [&](char* Bs, int k0) {
#pragma unroll
        for (int p = 0; p < 4; ++p) {
            int nr = w * 32 + p * 8 + (lane >> 3);
            int cp = ((lane & 7) * 16) ^ (((lane >> 3) & 7) << 4);  // source col in [0,128)
            const char* src = (cp < 64)
                ? (const char*)W1Th + (long long)nr * 1024 + k0 * 2 + cp
                : (const char*)W1Tl + (long long)nr * 1024 + k0 * 2 + (cp - 64);
            g7_gl2lds16(src, Bs + (w * 32 + p * 8) * 128);
        }
    };

    auto compute = [&](const char* As, const char* Bs) {
        bf16x8 a_hi[4], a_lo[4], b_hi[4], b_lo[4];
#pragma unroll
        for (int i = 0; i < 4; ++i) {
            int r = wr * 64 + i * 16 + la;
            int swz = (r & 7) << 4;
            const char* ab = As + r * 128;
            a_hi[i] = *(const bf16x8*)(ab + ((lk * 16) ^ swz));
            a_lo[i] = *(const bf16x8*)(ab + ((64 + lk * 16) ^ swz));
            int n = wc * 64 + i * 16 + la;
            int swzb = (n & 7) << 4;
            const char* bb = Bs + n * 128;
            b_hi[i] = *(const bf16x8*)(bb + ((lk * 16) ^ swzb));
            b_lo[i] = *(const bf16x8*)(bb + ((64 + lk * 16) ^ swzb));
        }
#pragma unroll
        for (int i = 0; i < 4; ++i)
#pragma unroll
            for (int j = 0; j < 4; ++j) {
                acc[i][j] = __builtin_amdgcn_mfma_f32_16x16x32_bf16(
                    a_hi[i], b_hi[j], acc[i][j], 0, 0, 0);
                acc[i][j] = __builtin_amdgcn_mfma_f32_16x16x32_bf16(
                    a_lo[i], b_hi[j], acc[i][j], 0, 0, 0);
                acc[i][j] = __builtin_amdgcn_mfma_f32_16x16x32_bf16(
                    a_hi[i], b_lo[j], acc[i][j], 0, 0, 0);
            }
    };

    // prologue: stage K-step 0 into buffer 0
    loadA(0);
    stageB(smc + 16384, 0);
    writeA(smc);
    __syncthreads();                      // drains vmcnt: buf0 ready

    for (int kt = 0; kt < 16; ++kt) {
        char* bc = smc + (kt & 1) * 32768;
        char* bn = smc + ((kt & 1) ^ 1) * 32768;
        if (kt < 15) {                    // issue next-tile loads early (T14)
            loadA((kt + 1) * 32);
            stageB(bn + 16384, (kt + 1) * 32);
        }
        compute(bc, bc + 16384);
        if (kt < 15) writeA(bn);          // convert-late: vmcnt wait lands here
        __syncthreads();
    }

    // epilogue: D row = lk*4+q (m), col = la (n) per 16x16 fragment; bf16 store
#pragma unroll
    for (int i = 0; i < 4; ++i) {
#pragma unroll
        for (int j = 0; j < 4; ++j) {
            int n = wc * 64 + j * 16 + la;
#pragma unroll
            for (int q = 0; q < 4; ++q) {
                int m = m0 + wr * 64 + i * 16 + lk * 4 + q;
                if (m < N_NODES) {
                    h1b[(long long)m * F_HID + n] = g7_f2bf(acc[i][j][q]);
                }
            }
        }
    }
}

// ---- agg1 CSR gather, bf16 table, dual-edge halves + 2-wide unroll.
// Wave = 1 node; lane fl owns 4 features. Self-loop folded as edge w=dinv[d]. ----
__global__ void g7_agg1(const int* rowptr, const int* csr, const float* dinv,
                        const unsigned short* h1b, const float* b1, float* r1) {
    int node = blockIdx.x * 4 + (threadIdx.x >> 6);
    int lane = threadIdx.x & 63;
    int e = lane >> 5;
    int fl = lane & 31;
    if (node >= N_NODES) return;
    int beg = rowptr[node];
    int end = rowptr[node + 1];
    const uint2* hv = (const uint2*)h1b;   // row = 32 uint2
    float a0 = 0.f, a1 = 0.f, a2 = 0.f, a3 = 0.f;
    int j = beg + e;
    for (; j + 2 < end; j += 4) {
        int s0 = csr[j];
        int s1 = csr[j + 2];
        float w0 = dinv[s0];
        float w1 = dinv[s1];
        uint2 v0 = hv[(long long)s0 * 32 + fl];
        uint2 v1 = hv[(long long)s1 * 32 + fl];
        float2 p0 = g7_up(v0.x), q0 = g7_up(v0.y);
        float2 p1 = g7_up(v1.x), q1 = g7_up(v1.y);
        a0 += p0.x * w0 + p1.x * w1;
        a1 += p0.y * w0 + p1.y * w1;
        a2 += q0.x * w0 + q1.x * w1;
        a3 += q0.y * w0 + q1.y * w1;
    }
    if (j < end) {
        int s0 = csr[j];
        float w0 = dinv[s0];
        uint2 v0 = hv[(long long)s0 * 32 + fl];
        float2 p0 = g7_up(v0.x), q0 = g7_up(v0.y);
        a0 += p0.x * w0;
        a1 += p0.y * w0;
        a2 += q0.x * w0;
        a3 += q0.y * w0;
    }
    float di = dinv[node];
    if (e == 0) {                     // self-loop as an edge with w = dinv[node]
        uint2 vd = hv[(long long)node * 32 + fl];
        float2 pd = g7_up(vd.x), qd = g7_up(vd.y);
        a0 += pd.x * di;
        a1 += pd.y * di;
        a2 += qd.x * di;
        a3 += qd.y * di;
    }
    a0 += __shfl_xor(a0, 32);
    a1 += __shfl_xor(a1, 32);
    a2 += __shfl_xor(a2, 32);
    a3 += __shfl_xor(a3, 32);
    if (e == 0) {
        float4 bb = *(const float4*)(b1 + 4 * fl);
        float r0 = a0 * di + bb.x;
        float r1v = a1 * di + bb.y;
        float r2 = a2 * di + bb.z;
        float r3 = a3 * di + bb.w;
        if (r0 < 0.f) r0 = 0.f;
        if (r1v < 0.f) r1v = 0.f;
        if (r2 < 0.f) r2 = 0.f;
        if (r3 < 0.f) r3 = 0.f;
        float4 o;
        o.x = r0; o.y = r1v; o.z = r2; o.w = r3;
        *(float4*)(r1 + (long long)node * F_HID + 4 * fl) = o;
    }
}

// ---- GEMM2: h2b[100000,64] (bf16) = r1 @ W2f. BM=64, BN=64, BK=32, 256 thr ----
__global__ void g7_gemm2(const float* r1, const float* W2, unsigned short* h2b) {
    __shared__ float Rs[32][68];
    __shared__ float Ws[32][64];
    int tid = threadIdx.x;
    int m0 = blockIdx.x * 64;
    int tx = tid & 15;
    int ty = tid >> 4;
    float acc[4][4];
#pragma unroll
    for (int i = 0; i < 4; ++i) {
#pragma unroll
        for (int j = 0; j < 4; ++j) acc[i][j] = 0.0f;
    }

    for (int k0 = 0; k0 < F_HID; k0 += 32) {
#pragma unroll
        for (int r = 0; r < 8; ++r) {
            int i = r * 256 + tid;
            int kk = i & 31;
            int mm = i >> 5;
            int m = m0 + mm;
            float v = 0.0f;
            if (m < N_NODES) {
                v = r1[(long long)m * F_HID + k0 + kk];
            }
            Rs[kk][mm] = v;
        }
#pragma unroll
        for (int r = 0; r < 8; ++r) {
            int i = r * 256 + tid;
            int wk = i >> 6;
            int wn = i & 63;
            Ws[wk][wn] = W2[(k0 + wk) * F_OUT + wn];
        }
        __syncthreads();
#pragma unroll
        for (int k = 0; k < 32; ++k) {
            float a[4];
            float b[4];
#pragma unroll
            for (int i = 0; i < 4; ++i) a[i] = Rs[k][ty * 4 + i];
#pragma unroll
            for (int j = 0; j < 4; ++j) b[j] = Ws[k][tx * 4 + j];
#pragma unroll
            for (int i = 0; i < 4; ++i) {
#pragma unroll
                for (int j = 0; j < 4; ++j) acc[i][j] += a[i] * b[j];
            }
        }
        __syncthreads();
    }
#pragma unroll
    for (int i = 0; i < 4; ++i) {
        int m = m0 + ty * 4 + i;
        if (m < N_NODES) {
            unsigned int w0 = (unsigned int)g7_f2bf(acc[i][0])
                            | ((unsigned int)g7_f2bf(acc[i][1]) << 16);
            unsigned int w1 = (unsigned int)g7_f2bf(acc[i][2])
                            | ((unsigned int)g7_f2bf(acc[i][3]) << 16);
            uint2 o; o.x = w0; o.y = w1;
            *(uint2*)(h2b + (long long)m * F_OUT + tx * 4) = o;
        }
    }
}

// ---- agg2 CSR gather (bf16 table) + final epilogue, dual-edge halves. ----
__global__ void g7_agg2(const int* rowptr, const int* csr, const float* dinv,
                        const unsigned short* h2b, const float* b2, const int* fflag,
                        void* out) {
    int node = blockIdx.x * 4 + (threadIdx.x >> 6);
    int lane = threadIdx.x & 63;
    int e = lane >> 5;
    int fl = lane & 31;
    if (node >= N_NODES) return;
    int beg = rowptr[node];
    int end = rowptr[node + 1];
    const u32* hv = (const u32*)h2b;   // row = 32 u32
    float a0 = 0.f, a1 = 0.f;
    int j = beg + e;
    for (; j + 2 < end; j += 4) {
        int s0 = csr[j];
        int s1 = csr[j + 2];
        float w0 = dinv[s0];
        float w1 = dinv[s1];
        u32 v0 = hv[(long long)s0 * 32 + fl];
        u32 v1 = hv[(long long)s1 * 32 + fl];
        float2 p0 = g7_up(v0);
        float2 p1 = g7_up(v1);
        a0 += p0.x * w0 + p1.x * w1;
        a1 += p0.y * w0 + p1.y * w1;
    }
    if (j < end) {
        int s0 = csr[j];
        float w0 = dinv[s0];
        u32 v0 = hv[(long long)s0 * 32 + fl];
        float2 p0 = g7_up(v0);
        a0 += p0.x * w0;
        a1 += p0.y * w0;
    }
    float di = dinv[node];
    if (e == 0) {
        u32 vd = hv[(long long)node * 32 + fl];
        float2 pd = g7_up(vd);
        a0 += pd.x * di;
        a1 += pd.y * di;
    }
    a0 += __shfl_xor(a0, 32);
    a1 += __shfl_xor(a1, 32);
    if (e == 0) {
        float v0 = a0 * di + b2[2 * fl];
        float v1 = a1 * di + b2[2 * fl + 1];
        long long oi = (long long)node * F_OUT + 2 * fl;
        if (fflag[0] == 1) {
            u32 o = (u32)g7_f2bf(v0) | ((u32)g7_f2bf(v1) << 16);
            *(u32*)((unsigned short*)out + oi) = o;
        } else {
            float2 o; o.x = v0; o.y = v1;
            *(float2*)((float*)out + oi) = o;
        }
    }
}

extern "C" void kernel_launch(void* const* d_in, const int* in_sizes, int n_in,
                              void* d_out, int out_size, void* d_ws, size_t ws_size,
                              hipStream_t stream) {
    const void* x     = d_in[0];
    const int* ei_raw = (const int*)d_in[1];
    const void* W1    = d_in[2];
    const void* b1    = d_in[3];
    const void* W2    = d_in[4];
    const void* b2    = d_in[5];

    const int NBLK = (N_NODES + 255) / 256;   // 391

    // workspace layout (byte offsets, 16B-aligned):
    char* ws = (char*)d_ws;
    int*   deg    = (int*)(ws + 0);            //    400,000 B
    int*   iflag  = (int*)(ws + 409600);       //          4 B
    int*   fflag  = (int*)(ws + 409616);       //          4 B
    int*   bsum   = (int*)(ws + 409632);       //      1,564 B
    int*   boff   = (int*)(ws + 412800);       //      1,564 B
    int*   bcur   = (int*)(ws + 450560);       //      1,564 B
    float* dinv   = (float*)(ws + 524288);     //    400,000 B
    unsigned short* W1Th = (unsigned short*)(ws + 1048576); // 131,072 B
    unsigned short* W1Tl = (unsigned short*)(ws + 1179648); // 131,072 B
    float* b1f    = (float*)(ws + 1310720);    //        512 B
    float* W2f    = (float*)(ws + 1311232);    //     32,768 B
    float* b2f    = (float*)(ws + 1344000);    //        256 B
    int*   ei     = (int*)(ws + 2097152);      // 12,800,000 B
    int*   rowptr = (int*)(ws + 14897152);     //    400,004 B
    int*   csr    = (int*)(ws + 16777216);     //  6,400,000 B
    unsigned short* h1b = (unsigned short*)(ws + 23177216); // 25,600,000 B
    uint2* part   = (uint2*)(ws + 50331648);   // 12,800,000 B
    float* r1     = (float*)(ws + 74377216);   // 51,200,000 B
    unsigned short* h2b = (unsigned short*)(ws + 125577216); // 12,800,000 B

    g7_zero<<<(N_NODES + 255) / 256, 256, 0, stream>>>(deg, N_NODES);

    g7_iprobe<<<1, 256, 0, stream>>>(ei_raw, iflag);
    g7_fprobe<<<1, 256, 0, stream>>>((const unsigned int*)x, fflag);

    // pack + fused degree count
    g7_pack<<<(2 * N_EDGES + 255) / 256, 256, 0, stream>>>(ei_raw, iflag, ei, deg);

    g7_cvt<<<1, 128, 0, stream>>>(b1, fflag, b1f, F_HID);
    g7_cvt<<<(F_HID * F_OUT + 255) / 256, 256, 0, stream>>>(W2, fflag, W2f, F_HID * F_OUT);
    g7_cvt<<<1, 64, 0, stream>>>(b2, fflag, b2f, F_OUT);
    g7_w1s<<<(F_IN * F_HID + 255) / 256, 256, 0, stream>>>(W1, fflag, W1Th, W1Tl);

    g7_dinv<<<(N_NODES + 255) / 256, 256, 0, stream>>>(deg, dinv);

    // CSR rowptr
    g7_bsum<<<NBLK, 256, 0, stream>>>(deg, bsum);
    g7_bscan<<<1, 512, 0, stream>>>(bsum, boff, NBLK, rowptr);
    g7_scan<<<NBLK, 256, 0, stream>>>(deg, boff, rowptr);

    // two-pass bucket partition (replaces direct scatter)
    g7_binit<<<(NBUK + 255) / 256, 256, 0, stream>>>(rowptr, bcur);
    g7_part1<<<(N_EDGES + P1_TILE - 1) / P1_TILE, 256, 0, stream>>>(ei, bcur, part);
    g7_part2<<<NBUK, 512, 0, stream>>>(rowptr, part, csr);

    // GEMM1: split-bf16 MFMA (fp32-class accuracy), bf16 output table
    g7_gemm1s<<<(N_NODES + 127) / 128, 256, 0, stream>>>(x, fflag, W1Th, W1Tl, h1b);

    g7_agg1<<<N_NODES / 4, 256, 0, stream>>>(rowptr, csr, dinv, h1b, b1f, r1);

    g7_gemm2<<<(N_NODES + 63) / 64, 256, 0, stream>>>(r1, W2f, h2b);

    g7_agg2<<<N_NODES / 4, 256, 0, stream>>>(rowptr, csr, dinv, h2b, b2f, fflag, d_out);
}